// Round 11
// baseline (166.783 us; speedup 1.0000x reference)
//
#include <hip/hip_runtime.h>

#define H 1024
#define HH (H * H)
#define BATCH 8192
#define NSTEPS 50

typedef __attribute__((ext_vector_type(8))) short bf16x8;
typedef __attribute__((ext_vector_type(4))) float f32x4;

// ---------------------------------------------------------------------------
// helpers
// ---------------------------------------------------------------------------
__device__ __forceinline__ void split2(float a, unsigned short& h, unsigned short& l)
{
    unsigned u = __float_as_uint(a);
    float r = a - __uint_as_float(u & 0xFFFF0000u);   // exact residual
    h = (unsigned short)(u >> 16);                    // truncated bf16
    l = (unsigned short)((__float_as_uint(r) + 0x8000u) >> 16); // rounded residual
}
__device__ __forceinline__ unsigned short rnd_bf16(float a)
{
    return (unsigned short)((__float_as_uint(a) + 0x8000u) >> 16);  // round-half-up
}
__device__ __forceinline__ float bf2f(unsigned short s)
{
    return __uint_as_float(((unsigned)s) << 16);
}
__device__ __forceinline__ void gload16(const void* g, void* l)
{
    __builtin_amdgcn_global_load_lds(
        (const __attribute__((address_space(1))) void*)g,
        (__attribute__((address_space(3))) void*)l, 16, 0, 0);
}
#define VMCNT(n) asm volatile("s_waitcnt vmcnt(" #n ")" ::: "memory")
#define RBAR() do { __builtin_amdgcn_s_barrier(); __builtin_amdgcn_sched_barrier(0); } while (0)

// ---------------------------------------------------------------------------
// setup: A = I + h*W as bf16 hi/lo planes, normal + transposed; cv/v0 = h*b.
// ---------------------------------------------------------------------------
__global__ void setup_k(const float* __restrict__ W, const float* __restrict__ bvec,
                        const float* __restrict__ t0, const float* __restrict__ t1,
                        unsigned short* __restrict__ Aplanes,
                        float* __restrict__ cv, float* __restrict__ v0)
{
    __shared__ unsigned short th[64][68], tl[64][68];
    const float h = (t1[0] - t0[0]) / (float)NSTEPS;
    const int bid = blockIdx.x, tid = threadIdx.x;
    const int rb = (bid >> 4) * 64, cb = (bid & 15) * 64;
    const int row = tid >> 2, c16 = (tid & 3) * 16;

    unsigned short* Ahi  = Aplanes;
    unsigned short* Alo  = Aplanes + HH;
    unsigned short* AhiT = Aplanes + 2 * HH;
    unsigned short* AloT = Aplanes + 3 * HH;

    {
        const float* wsrc = &W[(size_t)(rb + row) * H + cb + c16];
        bf16x8 hv[2], lv[2];
        #pragma unroll
        for (int q = 0; q < 16; ++q) {
            const float a = h * wsrc[q] + ((rb + row) == (cb + c16 + q) ? 1.0f : 0.0f);
            unsigned short hh, ll;
            split2(a, hh, ll);
            hv[q >> 3][q & 7] = (short)hh;
            lv[q >> 3][q & 7] = (short)ll;
            th[row][c16 + q] = hh;
            tl[row][c16 + q] = ll;
        }
        *(bf16x8*)&Ahi[(size_t)(rb + row) * H + cb + c16] = hv[0];
        *(bf16x8*)&Ahi[(size_t)(rb + row) * H + cb + c16 + 8] = hv[1];
        *(bf16x8*)&Alo[(size_t)(rb + row) * H + cb + c16] = lv[0];
        *(bf16x8*)&Alo[(size_t)(rb + row) * H + cb + c16 + 8] = lv[1];
    }
    __syncthreads();
    {
        bf16x8 hv[2], lv[2];
        #pragma unroll
        for (int q = 0; q < 16; ++q) {
            hv[q >> 3][q & 7] = (short)th[c16 + q][row];
            lv[q >> 3][q & 7] = (short)tl[c16 + q][row];
        }
        *(bf16x8*)&AhiT[(size_t)(cb + row) * H + rb + c16] = hv[0];
        *(bf16x8*)&AhiT[(size_t)(cb + row) * H + rb + c16 + 8] = hv[1];
        *(bf16x8*)&AloT[(size_t)(cb + row) * H + rb + c16] = lv[0];
        *(bf16x8*)&AloT[(size_t)(cb + row) * H + rb + c16 + 8] = lv[1];
    }
    if (bid == 0) {
        #pragma unroll
        for (int rep = 0; rep < 4; ++rep) {
            const int i = tid + rep * 256;
            const float v = h * bvec[i];
            cv[i] = v; v0[i] = v;
        }
    }
}

// ---------------------------------------------------------------------------
// fused chain step: 512 threads.
//  blocks [0,256):   Q = L * R  (64x64 tile, 8 waves, in-block split-K=2,
//                    2-buffer COUNTED-VMCNT pipeline: stage(t+2) issued after
//                    the post-MFMA barrier, VMCNT(4) before reads -> load
//                    latency hidden across a full iteration)
//  blocks [256,272): vout = addv + (Lhi+Llo) * vin
//  blocks [272,2320) (DO_X only): X fp32 -> transposed bf16 plane XhiT
// ---------------------------------------------------------------------------
template<bool WRITE_T, bool DO_X>
__launch_bounds__(512)
__global__ void chain_fused_k(const unsigned short* __restrict__ Lhi,
                              const unsigned short* __restrict__ Llo,
                              const unsigned short* __restrict__ RThi,
                              const unsigned short* __restrict__ RTlo,
                              unsigned short* __restrict__ Qhi,
                              unsigned short* __restrict__ Qlo,
                              unsigned short* __restrict__ QhiT,
                              unsigned short* __restrict__ QloT,
                              const float* __restrict__ vin,
                              const float* __restrict__ addv,
                              float* __restrict__ vout,
                              const float* __restrict__ X,
                              unsigned short* __restrict__ XhiT)
{
    __shared__ unsigned short sA[2][2][2][64][32];  // [dbuf][khalf][plane][row][k] 32KB
    __shared__ unsigned short sB[2][2][2][64][32];  // 32KB

    const int tid = threadIdx.x;
    const int bid = blockIdx.x;
    const int wave = tid >> 6, lane = tid & 63;

    if (DO_X && bid >= 272) {
        // ---- X transpose blocks: fp32 -> rounded bf16, transposed ----
        float (*ts)[65] = (float(*)[65])&sA[0][0][0][0][0];   // 16.6KB overlay
        const int tile = bid - 272;                            // 0..2047
        const int n0x = (tile >> 4) * 64, k0x = (tile & 15) * 64;
        #pragma unroll
        for (int p = 0; p < 2; ++p) {
            const int kr = p * 32 + (tid >> 4);     // k-local
            const int c4 = (tid & 15) * 4;          // n-local
            const float4 v = *(const float4*)&X[(size_t)(k0x + kr) * BATCH + n0x + c4];
            ts[kr][c4 + 0] = v.x; ts[kr][c4 + 1] = v.y;
            ts[kr][c4 + 2] = v.z; ts[kr][c4 + 3] = v.w;
        }
        __syncthreads();
        {
            const int n = tid >> 3;                 // n-local 0..63
            const int kc = (tid & 7) * 8;           // k-local chunk
            bf16x8 hv;
            #pragma unroll
            for (int q = 0; q < 8; ++q)
                hv[q] = (short)rnd_bf16(ts[kc + q][n]);
            *(bf16x8*)&XhiT[(size_t)(n0x + n) * H + k0x + kc] = hv;
        }
        return;
    }

    if (bid >= 256) {
        // ---- matvec blocks ----
        const int rowbase = (bid - 256) * 64 + wave * 8;
        const float4* xq = (const float4*)vin + lane * 4;
        float4 xv[4];
        #pragma unroll
        for (int q = 0; q < 4; ++q) xv[q] = xq[q];
        #pragma unroll
        for (int rr = 0; rr < 8; ++rr) {
            const int row = rowbase + rr;
            const unsigned short* mh = Lhi + (size_t)row * H + lane * 16;
            const unsigned short* ml = Llo + (size_t)row * H + lane * 16;
            bf16x8 h0 = *(const bf16x8*)&mh[0];
            bf16x8 h1 = *(const bf16x8*)&mh[8];
            bf16x8 l0 = *(const bf16x8*)&ml[0];
            bf16x8 l1 = *(const bf16x8*)&ml[8];
            float s = 0.0f;
            #pragma unroll
            for (int q = 0; q < 8; ++q) {
                const float m0v = bf2f((unsigned short)h0[q]) + bf2f((unsigned short)l0[q]);
                const float m1v = bf2f((unsigned short)h1[q]) + bf2f((unsigned short)l1[q]);
                const float* xf = (const float*)xv;
                s = fmaf(m0v, xf[q], s);
                s = fmaf(m1v, xf[8 + q], s);
            }
            #pragma unroll
            for (int off = 32; off; off >>= 1)
                s += __shfl_down(s, off, 64);
            if (lane == 0) vout[row] = addv[row] + s;
        }
        return;
    }

    // ---- GEMM blocks ----
    const int lg = lane >> 4, lm = lane & 15;
    const int half = wave >> 2;               // k-half owner
    const int wq = wave & 3;
    const int wr2 = (wq >> 1) * 32, wc2 = (wq & 1) * 32;
    // 2D patch per XCD
    const int xcd = bid & 7;
    const int idx0 = bid >> 3;
    const int mt = (xcd >> 1) * 4 + (idx0 & 3);
    const int nt = (xcd & 1) * 8 + (idx0 >> 2);
    const int m0 = mt * 64, n0 = nt * 64;

    f32x4 acc[2][2] = {};

    #define CSTAGE(tt, b) do {                                                   \
        _Pragma("unroll")                                                        \
        for (int it = 0; it < 4; ++it) {                                         \
            const int idx = tid + it * 512;                                      \
            const int mat = idx >> 10, kh = (idx >> 9) & 1;                      \
            const int plane = (idx >> 8) & 1;                                    \
            const int row = (idx >> 2) & 63, kc = idx & 3;                       \
            const int ks = kc ^ ((row >> 1) & 3);                                \
            const unsigned short* g = mat ? (plane ? RTlo : RThi)                \
                                          : (plane ? Llo : Lhi);                 \
            const int rb = mat ? n0 : m0;                                        \
            unsigned short* d = mat ? &sB[b][kh][plane][row][kc * 8]             \
                                    : &sA[b][kh][plane][row][kc * 8];            \
            gload16(g + (size_t)(rb + row) * H + kh * 512 + (tt) * 32 + ks * 8, d); \
        }                                                                        \
    } while (0)

    CSTAGE(0, 0);
    CSTAGE(1, 1);

    for (int t = 0; t < 16; ++t) {
        const int buf = t & 1;
        // own stage(t) complete (stage(t+1)'s 4 loads may remain in flight);
        // barrier then ensures ALL waves' stage(t) data has landed.
        if (t < 15) VMCNT(4); else VMCNT(0);
        RBAR();

        bf16x8 ah[2], al[2], bh[2], bl[2];
        #pragma unroll
        for (int i = 0; i < 2; ++i) {
            const int row = wr2 + i * 16 + lm;
            const int sl = lg ^ ((row >> 1) & 3);
            ah[i] = *(const bf16x8*)&sA[buf][half][0][row][sl * 8];
            al[i] = *(const bf16x8*)&sA[buf][half][1][row][sl * 8];
            const int rn = wc2 + i * 16 + lm;
            const int sn = lg ^ ((rn >> 1) & 3);
            bh[i] = *(const bf16x8*)&sB[buf][half][0][rn][sn * 8];
            bl[i] = *(const bf16x8*)&sB[buf][half][1][rn][sn * 8];
        }
        __builtin_amdgcn_s_setprio(1);
        #pragma unroll
        for (int i = 0; i < 2; ++i)
            #pragma unroll
            for (int j = 0; j < 2; ++j) {
                acc[i][j] = __builtin_amdgcn_mfma_f32_16x16x32_bf16(ah[i], bh[j], acc[i][j], 0, 0, 0);
                acc[i][j] = __builtin_amdgcn_mfma_f32_16x16x32_bf16(ah[i], bl[j], acc[i][j], 0, 0, 0);
                acc[i][j] = __builtin_amdgcn_mfma_f32_16x16x32_bf16(al[i], bh[j], acc[i][j], 0, 0, 0);
            }
        __builtin_amdgcn_s_setprio(0);
        // all waves done reading buf -> safe to overwrite it with stage(t+2)
        RBAR();
        if (t + 2 < 16) CSTAGE(t + 2, buf);
    }
    #undef CSTAGE

    // cross-half reduce via LDS (stride 17 floats)
    float* red = (float*)&sA[0][0][0][0][0];
    const int ridx = wq * 64 + lane;
    if (half == 1) {
        float* dst = red + (size_t)ridx * 17;
        #pragma unroll
        for (int i = 0; i < 2; ++i)
            #pragma unroll
            for (int j = 0; j < 2; ++j)
                *(f32x4*)&dst[(i * 2 + j) * 4] = acc[i][j];
    }
    __syncthreads();
    if (half == 0) {
        const float* src = red + (size_t)ridx * 17;
        #pragma unroll
        for (int i = 0; i < 2; ++i)
            #pragma unroll
            for (int j = 0; j < 2; ++j) {
                const f32x4 p = *(const f32x4*)&src[(i * 2 + j) * 4];
                acc[i][j] += p;
            }
        #pragma unroll
        for (int i = 0; i < 2; ++i) {
            const int row0 = m0 + wr2 + i * 16 + lg * 4;
            #pragma unroll
            for (int j = 0; j < 2; ++j) {
                const int col = n0 + wc2 + j * 16 + lm;
                unsigned short hs[4], ls[4];
                #pragma unroll
                for (int r = 0; r < 4; ++r) {
                    split2(acc[i][j][r], hs[r], ls[r]);
                    Qhi[(size_t)(row0 + r) * H + col] = hs[r];
                    Qlo[(size_t)(row0 + r) * H + col] = ls[r];
                }
                if (WRITE_T) {
                    ushort4 th, tl;
                    th.x = hs[0]; th.y = hs[1]; th.z = hs[2]; th.w = hs[3];
                    tl.x = ls[0]; tl.y = ls[1]; tl.z = ls[2]; tl.w = ls[3];
                    *(ushort4*)&QhiT[(size_t)col * H + row0] = th;
                    *(ushort4*)&QloT[(size_t)col * H + row0] = tl;
                }
            }
        }
    }
}

// ---------------------------------------------------------------------------
// big GEMM, pipelined, 2-product: C = (Phi+Plo) * Xh + bias.
// 128x256 tile, 8 waves (64x64 each), BK=32, 3-buffer counted-vmcnt pipe.
// ---------------------------------------------------------------------------
__launch_bounds__(512)
__global__ void big_gemm_pipe_k(const unsigned short* __restrict__ Phi,
                                const unsigned short* __restrict__ Plo,
                                const unsigned short* __restrict__ XhiT,
                                float* __restrict__ C, const float* __restrict__ bias)
{
    __shared__ unsigned short sA[3][2][128][32];   // [buf][plane][row][k] 48KB
    __shared__ unsigned short sB[3][256][32];      // [buf][row][k]        48KB

    const int tid = threadIdx.x;
    const int wave = tid >> 6, lane = tid & 63;
    const int lg = lane >> 4, lm = lane & 15;
    const int wr2 = (wave >> 2) * 64;    // m offset of wave tile (64 rows)
    const int wc2 = (wave & 3) * 64;     // n offset of wave tile (64 cols)
    const int bid = blockIdx.x;
    const int l = bid >> 3;
    const int m0 = (l & 7) * 128;
    const int n0 = ((bid & 7) * 4 + (l >> 3)) * 256;

    f32x4 acc[4][4] = {};

    #define BSTAGE(tt, b) do {                                                     \
        const int r_ = tid >> 2, kc_ = tid & 3;                                    \
        const int ks_ = kc_ ^ ((r_ >> 1) & 3);                                     \
        const size_t go_ = (size_t)(tt) * 32 + ks_ * 8;                            \
        gload16(Phi  + (size_t)(m0 + r_) * H + go_, &sA[b][0][r_][kc_ * 8]);       \
        gload16(Plo  + (size_t)(m0 + r_) * H + go_, &sA[b][1][r_][kc_ * 8]);       \
        gload16(XhiT + (size_t)(n0 + r_) * H + go_, &sB[b][r_][kc_ * 8]);          \
        gload16(XhiT + (size_t)(n0 + 128 + r_) * H + go_, &sB[b][128 + r_][kc_ * 8]); \
    } while (0)

    BSTAGE(0, 0);
    BSTAGE(1, 1);
    VMCNT(4);
    RBAR();

    #pragma unroll
    for (int t = 0; t < 32; ++t) {
        const int b = t % 3;
        bf16x8 ah[4], al[4], bh[4];
        #pragma unroll
        for (int i = 0; i < 4; ++i) {
            const int row = wr2 + i * 16 + lm;
            const int sl = lg ^ ((row >> 1) & 3);
            ah[i] = *(const bf16x8*)&sA[b][0][row][sl * 8];
            al[i] = *(const bf16x8*)&sA[b][1][row][sl * 8];
        }
        #pragma unroll
        for (int j = 0; j < 4; ++j) {
            const int rn = wc2 + j * 16 + lm;
            const int sn = lg ^ ((rn >> 1) & 3);
            bh[j] = *(const bf16x8*)&sB[b][rn][sn * 8];
        }
        if (t + 2 < 32) BSTAGE(t + 2, (t + 2) % 3);
        __builtin_amdgcn_s_setprio(1);
        #pragma unroll
        for (int i = 0; i < 4; ++i)
            #pragma unroll
            for (int j = 0; j < 4; ++j) {
                acc[i][j] = __builtin_amdgcn_mfma_f32_16x16x32_bf16(ah[i], bh[j], acc[i][j], 0, 0, 0);
                acc[i][j] = __builtin_amdgcn_mfma_f32_16x16x32_bf16(al[i], bh[j], acc[i][j], 0, 0, 0);
            }
        __builtin_amdgcn_s_setprio(0);
        if (t < 30) VMCNT(4);
        else if (t == 30) VMCNT(0);
        if (t < 31) RBAR();
    }
    #undef BSTAGE

    #pragma unroll
    for (int i = 0; i < 4; ++i) {
        const int row0 = m0 + wr2 + i * 16 + lg * 4;
        #pragma unroll
        for (int r = 0; r < 4; ++r) {
            const float bv = bias[row0 + r];
            float* dst = &C[(size_t)(row0 + r) * BATCH + n0 + wc2 + lm];
            #pragma unroll
            for (int j = 0; j < 4; ++j)
                dst[j * 16] = acc[i][j][r] + bv;
        }
    }
}

// ---------------------------------------------------------------------------
// big GEMM fallback (X split in-kernel, no XT needed) — 3-product
// ---------------------------------------------------------------------------
#define PADK 40

__launch_bounds__(256)
__global__ void big_gemm_k(const unsigned short* __restrict__ Ahi_g,
                           const unsigned short* __restrict__ Alo_g,
                           const float* __restrict__ X, float* __restrict__ C,
                           const float* __restrict__ bias)
{
    __shared__ unsigned short Ahi[128][PADK], Alo[128][PADK];
    __shared__ unsigned short Bhi[128][PADK], Blo[128][PADK];

    const int tid = threadIdx.x;
    const int wave = tid >> 6;
    const int lane = tid & 63;
    const int wr = (wave >> 1) * 64;
    const int wc = (wave & 1) * 64;
    const int m0 = blockIdx.y * 128;
    const int n0 = blockIdx.x * 128;
    const int lg = lane >> 4;
    const int lm = lane & 15;

    f32x4 acc[4][4] = {};

    for (int k0 = 0; k0 < H; k0 += 32) {
        #pragma unroll
        for (int a2 = 0; a2 < 2; ++a2) {
            const int id = tid + a2 * 256;
            const int row = id >> 2;
            const int ko = id & 3;
            const size_t g = (size_t)(m0 + row) * H + k0 + ko * 8;
            *(bf16x8*)&Ahi[row][ko * 8] = *(const bf16x8*)&Ahi_g[g];
            *(bf16x8*)&Alo[row][ko * 8] = *(const bf16x8*)&Alo_g[g];
        }
        #pragma unroll
        for (int a2 = 0; a2 < 2; ++a2) {
            const int id = tid + a2 * 256;
            const int n = id & 127;
            const int ko = id >> 7;
            const float* src = &X[(size_t)(k0 + ko * 8) * BATCH + n0 + n];
            bf16x8 bh, bl;
            #pragma unroll
            for (int i = 0; i < 8; ++i) {
                unsigned short hh, ll;
                split2(src[(size_t)i * BATCH], hh, ll);
                bh[i] = (short)hh;
                bl[i] = (short)ll;
            }
            *(bf16x8*)&Bhi[n][ko * 8] = bh;
            *(bf16x8*)&Blo[n][ko * 8] = bl;
        }
        __syncthreads();

        bf16x8 ah[4], al[4], bh[4], bl[4];
        #pragma unroll
        for (int i = 0; i < 4; ++i) {
            const int m = wr + i * 16 + lm;
            ah[i] = *(const bf16x8*)&Ahi[m][lg * 8];
            al[i] = *(const bf16x8*)&Alo[m][lg * 8];
            const int n = wc + i * 16 + lm;
            bh[i] = *(const bf16x8*)&Bhi[n][lg * 8];
            bl[i] = *(const bf16x8*)&Blo[n][lg * 8];
        }
        #pragma unroll
        for (int i = 0; i < 4; ++i)
            #pragma unroll
            for (int j = 0; j < 4; ++j) {
                acc[i][j] = __builtin_amdgcn_mfma_f32_16x16x32_bf16(ah[i], bh[j], acc[i][j], 0, 0, 0);
                acc[i][j] = __builtin_amdgcn_mfma_f32_16x16x32_bf16(ah[i], bl[j], acc[i][j], 0, 0, 0);
                acc[i][j] = __builtin_amdgcn_mfma_f32_16x16x32_bf16(al[i], bh[j], acc[i][j], 0, 0, 0);
            }
        __syncthreads();
    }

    #pragma unroll
    for (int i = 0; i < 4; ++i) {
        const int rowb = m0 + wr + i * 16 + lg * 4;
        #pragma unroll
        for (int r = 0; r < 4; ++r) {
            const float bv = bias[rowb + r];
            float* dst = &C[(size_t)(rowb + r) * BATCH + n0 + wc + lm];
            #pragma unroll
            for (int j = 0; j < 4; ++j)
                dst[j * 16] = acc[i][j][r] + bv;
        }
    }
}

// ---------------------------------------------------------------------------
// host-side launcher
// ---------------------------------------------------------------------------
extern "C" void kernel_launch(void* const* d_in, const int* in_sizes, int n_in,
                              void* d_out, int out_size, void* d_ws, size_t ws_size,
                              hipStream_t stream)
{
    const float* x0 = (const float*)d_in[0];
    const float* t0 = (const float*)d_in[1];
    const float* t1 = (const float*)d_in[2];
    const float* W  = (const float*)d_in[3];
    const float* bb = (const float*)d_in[4];
    float* out = (float*)d_out;

    // ws layout: A planes {hi,lo,hiT,loT} (8MB) | cv,v0,v1 | @16MB: XhiT (16MB)
    unsigned short* Aplanes = (unsigned short*)d_ws;
    unsigned short* Ahi  = Aplanes;
    unsigned short* Alo  = Aplanes + HH;
    float* cv = (float*)(Aplanes + 4 * HH);
    float* v0 = cv + H;
    float* v1 = v0 + H;

    const size_t xtoff = (size_t)16 * 1024 * 1024;
    const bool useXT = ws_size >= xtoff + (size_t)BATCH * H * sizeof(unsigned short);
    unsigned short* XhiT = (unsigned short*)((char*)d_ws + xtoff);

    // d_out scratch: two ping-pong plane-sets {hi,lo,hiT,loT}, 8MB each (16MB),
    // fully overwritten by the final 32MB C write.
    unsigned short* PA = (unsigned short*)d_out;
    unsigned short* PB = PA + (size_t)4 * HH;

    setup_k<<<256, 256, 0, stream>>>(W, bb, t0, t1, Aplanes, cv, v0);

    // addition chain 1 -> 2 -> 3 -> 6 -> 12 -> 24 -> 25 -> 50
    const int seq[7] = {0, 1, 0, 0, 0, 1, 0};   // 0=SQ, 1=MUL
    unsigned short* cur = Ahi;                  // P_1 = A (4 consecutive planes)
    float* vin = v0;
    float* vout = v1;
    for (int s = 0; s < 7; ++s) {
        const unsigned short* L  = seq[s] ? Ahi : cur;
        const unsigned short* Ll = seq[s] ? Alo : cur + HH;
        const float* addv = seq[s] ? cv : vin;
        if (s == 0) {
            unsigned short* nxt = PA;
            if (useXT) {
                chain_fused_k<true, true><<<2320, 512, 0, stream>>>(
                    L, Ll, cur + 2 * HH, cur + 3 * HH,
                    nxt, nxt + HH, nxt + 2 * HH, nxt + 3 * HH,
                    vin, addv, vout, x0, XhiT);
            } else {
                chain_fused_k<true, false><<<272, 512, 0, stream>>>(
                    L, Ll, cur + 2 * HH, cur + 3 * HH,
                    nxt, nxt + HH, nxt + 2 * HH, nxt + 3 * HH,
                    vin, addv, vout, nullptr, nullptr);
            }
            cur = nxt;
        } else if (s < 6) {
            unsigned short* nxt = (s & 1) ? PB : PA;
            chain_fused_k<true, false><<<272, 512, 0, stream>>>(
                L, Ll, cur + 2 * HH, cur + 3 * HH,
                nxt, nxt + HH, nxt + 2 * HH, nxt + 3 * HH,
                vin, addv, vout, nullptr, nullptr);
            cur = nxt;
        } else {
            chain_fused_k<false, false><<<272, 512, 0, stream>>>(
                L, Ll, cur + 2 * HH, cur + 3 * HH,
                Ahi, Alo, nullptr, nullptr,
                vin, addv, vout, nullptr, nullptr);
            cur = Ahi;
        }
        float* tv = vin; vin = vout; vout = tv;
    }
    // cur = P_50 planes (in ws); vin = v_50

    if (useXT) {
        big_gemm_pipe_k<<<256, 512, 0, stream>>>(Ahi, Alo, XhiT, out, vin);
    } else {
        big_gemm_k<<<dim3(BATCH / 128, H / 128), 256, 0, stream>>>(
            Ahi, Alo, x0, out, vin);
    }
}

// Round 12
// 157.191 us; speedup vs baseline: 1.0610x; 1.0610x over previous
//
#include <hip/hip_runtime.h>

#define H 1024
#define HH (H * H)
#define BATCH 8192
#define NSTEPS 50

typedef __attribute__((ext_vector_type(8))) short bf16x8;
typedef __attribute__((ext_vector_type(4))) float f32x4;

// ---------------------------------------------------------------------------
// helpers
// ---------------------------------------------------------------------------
__device__ __forceinline__ void split2(float a, unsigned short& h, unsigned short& l)
{
    unsigned u = __float_as_uint(a);
    float r = a - __uint_as_float(u & 0xFFFF0000u);   // exact residual
    h = (unsigned short)(u >> 16);                    // truncated bf16
    l = (unsigned short)((__float_as_uint(r) + 0x8000u) >> 16); // rounded residual
}
__device__ __forceinline__ unsigned short rnd_bf16(float a)
{
    return (unsigned short)((__float_as_uint(a) + 0x8000u) >> 16);  // round-half-up
}
__device__ __forceinline__ float bf2f(unsigned short s)
{
    return __uint_as_float(((unsigned)s) << 16);
}
__device__ __forceinline__ void gload16(const void* g, void* l)
{
    __builtin_amdgcn_global_load_lds(
        (const __attribute__((address_space(1))) void*)g,
        (__attribute__((address_space(3))) void*)l, 16, 0, 0);
}

// ---------------------------------------------------------------------------
// setup: A = I + h*W as bf16 hi/lo planes, normal + transposed; cv/v0 = h*b.
// ---------------------------------------------------------------------------
__global__ void setup_k(const float* __restrict__ W, const float* __restrict__ bvec,
                        const float* __restrict__ t0, const float* __restrict__ t1,
                        unsigned short* __restrict__ Aplanes,
                        float* __restrict__ cv, float* __restrict__ v0)
{
    __shared__ unsigned short th[64][68], tl[64][68];
    const float h = (t1[0] - t0[0]) / (float)NSTEPS;
    const int bid = blockIdx.x, tid = threadIdx.x;
    const int rb = (bid >> 4) * 64, cb = (bid & 15) * 64;
    const int row = tid >> 2, c16 = (tid & 3) * 16;

    unsigned short* Ahi  = Aplanes;
    unsigned short* Alo  = Aplanes + HH;
    unsigned short* AhiT = Aplanes + 2 * HH;
    unsigned short* AloT = Aplanes + 3 * HH;

    {
        const float* wsrc = &W[(size_t)(rb + row) * H + cb + c16];
        bf16x8 hv[2], lv[2];
        #pragma unroll
        for (int q = 0; q < 16; ++q) {
            const float a = h * wsrc[q] + ((rb + row) == (cb + c16 + q) ? 1.0f : 0.0f);
            unsigned short hh, ll;
            split2(a, hh, ll);
            hv[q >> 3][q & 7] = (short)hh;
            lv[q >> 3][q & 7] = (short)ll;
            th[row][c16 + q] = hh;
            tl[row][c16 + q] = ll;
        }
        *(bf16x8*)&Ahi[(size_t)(rb + row) * H + cb + c16] = hv[0];
        *(bf16x8*)&Ahi[(size_t)(rb + row) * H + cb + c16 + 8] = hv[1];
        *(bf16x8*)&Alo[(size_t)(rb + row) * H + cb + c16] = lv[0];
        *(bf16x8*)&Alo[(size_t)(rb + row) * H + cb + c16 + 8] = lv[1];
    }
    __syncthreads();
    {
        bf16x8 hv[2], lv[2];
        #pragma unroll
        for (int q = 0; q < 16; ++q) {
            hv[q >> 3][q & 7] = (short)th[c16 + q][row];
            lv[q >> 3][q & 7] = (short)tl[c16 + q][row];
        }
        *(bf16x8*)&AhiT[(size_t)(cb + row) * H + rb + c16] = hv[0];
        *(bf16x8*)&AhiT[(size_t)(cb + row) * H + rb + c16 + 8] = hv[1];
        *(bf16x8*)&AloT[(size_t)(cb + row) * H + rb + c16] = lv[0];
        *(bf16x8*)&AloT[(size_t)(cb + row) * H + rb + c16 + 8] = lv[1];
    }
    if (bid == 0) {
        #pragma unroll
        for (int rep = 0; rep < 4; ++rep) {
            const int i = tid + rep * 256;
            const float v = h * bvec[i];
            cv[i] = v; v0[i] = v;
        }
    }
}

// ---------------------------------------------------------------------------
// fused chain step (round-10 proven structure): 512 threads.
//  blocks [0,256):   Q = L * R  (64x64 tile, 8 waves, in-block split-K=2,
//                    2-buffer __syncthreads staging via gload_lds, 3-product)
//  blocks [256,272): vout = addv + (Lhi+Llo) * vin
//  blocks [272,2320) (DO_X only): X fp32 -> transposed bf16 plane XhiT
// Epilogue: PR -> write single rounded bf16 plane to Qhi (final step, the
// only consumer is the bf16 big GEMM); else hi/lo planes (+T if WRITE_T).
// ---------------------------------------------------------------------------
template<bool WRITE_T, bool DO_X, bool PR>
__launch_bounds__(512)
__global__ void chain_fused_k(const unsigned short* __restrict__ Lhi,
                              const unsigned short* __restrict__ Llo,
                              const unsigned short* __restrict__ RThi,
                              const unsigned short* __restrict__ RTlo,
                              unsigned short* __restrict__ Qhi,
                              unsigned short* __restrict__ Qlo,
                              unsigned short* __restrict__ QhiT,
                              unsigned short* __restrict__ QloT,
                              const float* __restrict__ vin,
                              const float* __restrict__ addv,
                              float* __restrict__ vout,
                              const float* __restrict__ X,
                              unsigned short* __restrict__ XhiT)
{
    __shared__ unsigned short sA[2][2][2][64][32];  // [dbuf][khalf][plane][row][k] 32KB
    __shared__ unsigned short sB[2][2][2][64][32];  // 32KB

    const int tid = threadIdx.x;
    const int bid = blockIdx.x;
    const int wave = tid >> 6, lane = tid & 63;

    if (DO_X && bid >= 272) {
        // ---- X transpose blocks: fp32 -> rounded bf16, transposed ----
        float (*ts)[65] = (float(*)[65])&sA[0][0][0][0][0];   // 16.6KB overlay
        const int tile = bid - 272;                            // 0..2047
        const int n0x = (tile >> 4) * 64, k0x = (tile & 15) * 64;
        #pragma unroll
        for (int p = 0; p < 2; ++p) {
            const int kr = p * 32 + (tid >> 4);     // k-local
            const int c4 = (tid & 15) * 4;          // n-local
            const float4 v = *(const float4*)&X[(size_t)(k0x + kr) * BATCH + n0x + c4];
            ts[kr][c4 + 0] = v.x; ts[kr][c4 + 1] = v.y;
            ts[kr][c4 + 2] = v.z; ts[kr][c4 + 3] = v.w;
        }
        __syncthreads();
        {
            const int n = tid >> 3;                 // n-local 0..63
            const int kc = (tid & 7) * 8;           // k-local chunk
            bf16x8 hv;
            #pragma unroll
            for (int q = 0; q < 8; ++q)
                hv[q] = (short)rnd_bf16(ts[kc + q][n]);
            *(bf16x8*)&XhiT[(size_t)(n0x + n) * H + k0x + kc] = hv;
        }
        return;
    }

    if (bid >= 256) {
        // ---- matvec blocks ----
        const int rowbase = (bid - 256) * 64 + wave * 8;
        const float4* xq = (const float4*)vin + lane * 4;
        float4 xv[4];
        #pragma unroll
        for (int q = 0; q < 4; ++q) xv[q] = xq[q];
        #pragma unroll
        for (int rr = 0; rr < 8; ++rr) {
            const int row = rowbase + rr;
            const unsigned short* mh = Lhi + (size_t)row * H + lane * 16;
            const unsigned short* ml = Llo + (size_t)row * H + lane * 16;
            bf16x8 h0 = *(const bf16x8*)&mh[0];
            bf16x8 h1 = *(const bf16x8*)&mh[8];
            bf16x8 l0 = *(const bf16x8*)&ml[0];
            bf16x8 l1 = *(const bf16x8*)&ml[8];
            float s = 0.0f;
            #pragma unroll
            for (int q = 0; q < 8; ++q) {
                const float m0v = bf2f((unsigned short)h0[q]) + bf2f((unsigned short)l0[q]);
                const float m1v = bf2f((unsigned short)h1[q]) + bf2f((unsigned short)l1[q]);
                const float* xf = (const float*)xv;
                s = fmaf(m0v, xf[q], s);
                s = fmaf(m1v, xf[8 + q], s);
            }
            #pragma unroll
            for (int off = 32; off; off >>= 1)
                s += __shfl_down(s, off, 64);
            if (lane == 0) vout[row] = addv[row] + s;
        }
        return;
    }

    // ---- GEMM blocks ----
    const int lg = lane >> 4, lm = lane & 15;
    const int half = wave >> 2;               // k-half owner
    const int wq = wave & 3;
    const int wr2 = (wq >> 1) * 32, wc2 = (wq & 1) * 32;
    // 2D patch per XCD
    const int xcd = bid & 7;
    const int idx0 = bid >> 3;
    const int mt = (xcd >> 1) * 4 + (idx0 & 3);
    const int nt = (xcd & 1) * 8 + (idx0 >> 2);
    const int m0 = mt * 64, n0 = nt * 64;

    f32x4 acc[2][2] = {};

    #define CSTAGE(tt, b) do {                                                   \
        _Pragma("unroll")                                                        \
        for (int it = 0; it < 4; ++it) {                                         \
            const int idx = tid + it * 512;                                      \
            const int mat = idx >> 10, kh = (idx >> 9) & 1;                      \
            const int plane = (idx >> 8) & 1;                                    \
            const int row = (idx >> 2) & 63, kc = idx & 3;                       \
            const int ks = kc ^ ((row >> 1) & 3);                                \
            const unsigned short* g = mat ? (plane ? RTlo : RThi)                \
                                          : (plane ? Llo : Lhi);                 \
            const int rb = mat ? n0 : m0;                                        \
            unsigned short* d = mat ? &sB[b][kh][plane][row][kc * 8]             \
                                    : &sA[b][kh][plane][row][kc * 8];            \
            gload16(g + (size_t)(rb + row) * H + kh * 512 + (tt) * 32 + ks * 8, d); \
        }                                                                        \
    } while (0)

    CSTAGE(0, 0);
    __syncthreads();
    int buf = 0;
    for (int t = 0; t < 16; ++t) {
        if (t + 1 < 16) CSTAGE(t + 1, buf ^ 1);
        bf16x8 ah[2], al[2], bh[2], bl[2];
        #pragma unroll
        for (int i = 0; i < 2; ++i) {
            const int row = wr2 + i * 16 + lm;
            const int sl = lg ^ ((row >> 1) & 3);
            ah[i] = *(const bf16x8*)&sA[buf][half][0][row][sl * 8];
            al[i] = *(const bf16x8*)&sA[buf][half][1][row][sl * 8];
            const int rn = wc2 + i * 16 + lm;
            const int sn = lg ^ ((rn >> 1) & 3);
            bh[i] = *(const bf16x8*)&sB[buf][half][0][rn][sn * 8];
            bl[i] = *(const bf16x8*)&sB[buf][half][1][rn][sn * 8];
        }
        #pragma unroll
        for (int i = 0; i < 2; ++i)
            #pragma unroll
            for (int j = 0; j < 2; ++j) {
                acc[i][j] = __builtin_amdgcn_mfma_f32_16x16x32_bf16(ah[i], bh[j], acc[i][j], 0, 0, 0);
                acc[i][j] = __builtin_amdgcn_mfma_f32_16x16x32_bf16(ah[i], bl[j], acc[i][j], 0, 0, 0);
                acc[i][j] = __builtin_amdgcn_mfma_f32_16x16x32_bf16(al[i], bh[j], acc[i][j], 0, 0, 0);
            }
        __syncthreads();
        buf ^= 1;
    }
    #undef CSTAGE

    // cross-half reduce via LDS (stride 17 floats)
    float* red = (float*)&sA[0][0][0][0][0];
    const int ridx = wq * 64 + lane;
    if (half == 1) {
        float* dst = red + (size_t)ridx * 17;
        #pragma unroll
        for (int i = 0; i < 2; ++i)
            #pragma unroll
            for (int j = 0; j < 2; ++j)
                *(f32x4*)&dst[(i * 2 + j) * 4] = acc[i][j];
    }
    __syncthreads();
    if (half == 0) {
        const float* src = red + (size_t)ridx * 17;
        #pragma unroll
        for (int i = 0; i < 2; ++i)
            #pragma unroll
            for (int j = 0; j < 2; ++j) {
                const f32x4 p = *(const f32x4*)&src[(i * 2 + j) * 4];
                acc[i][j] += p;
            }
        #pragma unroll
        for (int i = 0; i < 2; ++i) {
            const int row0 = m0 + wr2 + i * 16 + lg * 4;
            #pragma unroll
            for (int j = 0; j < 2; ++j) {
                const int col = n0 + wc2 + j * 16 + lm;
                if (PR) {
                    // final step: single rounded bf16 plane (big GEMM input)
                    #pragma unroll
                    for (int r = 0; r < 4; ++r)
                        Qhi[(size_t)(row0 + r) * H + col] = rnd_bf16(acc[i][j][r]);
                } else {
                    unsigned short hs[4], ls[4];
                    #pragma unroll
                    for (int r = 0; r < 4; ++r) {
                        split2(acc[i][j][r], hs[r], ls[r]);
                        Qhi[(size_t)(row0 + r) * H + col] = hs[r];
                        Qlo[(size_t)(row0 + r) * H + col] = ls[r];
                    }
                    if (WRITE_T) {
                        ushort4 th, tl;
                        th.x = hs[0]; th.y = hs[1]; th.z = hs[2]; th.w = hs[3];
                        tl.x = ls[0]; tl.y = ls[1]; tl.z = ls[2]; tl.w = ls[3];
                        *(ushort4*)&QhiT[(size_t)col * H + row0] = th;
                        *(ushort4*)&QloT[(size_t)col * H + row0] = tl;
                    }
                }
            }
        }
    }
}

// ---------------------------------------------------------------------------
// big GEMM, bf16 x bf16 (1 MFMA per fragment): C = Pr * Xh + bias.
// Pr = round(P_50) single plane, XhT = round(X)^T single plane.
// 128x128 tile, 256 threads (4 waves, 64x64 each), BK=32, 2-buffer
// __syncthreads staging; grid 512 = 2 blocks/CU -> cross-block overlap
// hides the barrier drain (m114). 32KB LDS.
// XCD swizzle: 8 n-tiles per XCD (XT slice 2MB, L2-resident), m-inner.
// ---------------------------------------------------------------------------
__launch_bounds__(256)
__global__ void big_gemm1_k(const unsigned short* __restrict__ Pr,
                            const unsigned short* __restrict__ XhiT,
                            float* __restrict__ C, const float* __restrict__ bias)
{
    __shared__ unsigned short sA[2][128][32];   // 16KB
    __shared__ unsigned short sB[2][128][32];   // 16KB

    const int tid = threadIdx.x;
    const int wave = tid >> 6, lane = tid & 63;
    const int lg = lane >> 4, lm = lane & 15;
    const int wr2 = (wave >> 1) * 64;    // wave tile 64x64
    const int wc2 = (wave & 1) * 64;
    const int bid = blockIdx.x;
    // XCD x (bid&7) owns n-tiles [8x, 8x+8); m varies fastest within the XCD.
    const int l = bid >> 3;              // 0..63
    const int m0 = (l & 7) * 128;
    const int n0 = ((bid & 7) * 8 + (l >> 3)) * 128;

    f32x4 acc[4][4] = {};

    #define BSTAGE(tt, b) do {                                                   \
        _Pragma("unroll")                                                        \
        for (int it = 0; it < 2; ++it) {                                         \
            const int idx = tid + it * 256;                                      \
            const int row = idx >> 2, kc = idx & 3;                              \
            const int ks = kc ^ ((row >> 1) & 3);                                \
            const size_t go = (size_t)(tt) * 32 + ks * 8;                        \
            gload16(Pr   + (size_t)(m0 + row) * H + go, &sA[b][row][kc * 8]);    \
            gload16(XhiT + (size_t)(n0 + row) * H + go, &sB[b][row][kc * 8]);    \
        }                                                                        \
    } while (0)

    BSTAGE(0, 0);
    __syncthreads();
    int buf = 0;
    for (int t = 0; t < 32; ++t) {
        if (t + 1 < 32) BSTAGE(t + 1, buf ^ 1);
        bf16x8 ah[4], bh[4];
        #pragma unroll
        for (int i = 0; i < 4; ++i) {
            const int row = wr2 + i * 16 + lm;
            const int sl = lg ^ ((row >> 1) & 3);
            ah[i] = *(const bf16x8*)&sA[buf][row][sl * 8];
            const int rn = wc2 + i * 16 + lm;
            const int sn = lg ^ ((rn >> 1) & 3);
            bh[i] = *(const bf16x8*)&sB[buf][rn][sn * 8];
        }
        __builtin_amdgcn_s_setprio(1);
        #pragma unroll
        for (int i = 0; i < 4; ++i)
            #pragma unroll
            for (int j = 0; j < 4; ++j)
                acc[i][j] = __builtin_amdgcn_mfma_f32_16x16x32_bf16(ah[i], bh[j], acc[i][j], 0, 0, 0);
        __builtin_amdgcn_s_setprio(0);
        __syncthreads();
        buf ^= 1;
    }
    #undef BSTAGE

    #pragma unroll
    for (int i = 0; i < 4; ++i) {
        const int row0 = m0 + wr2 + i * 16 + lg * 4;
        #pragma unroll
        for (int r = 0; r < 4; ++r) {
            const float bv = bias[row0 + r];
            float* dst = &C[(size_t)(row0 + r) * BATCH + n0 + wc2 + lm];
            #pragma unroll
            for (int j = 0; j < 4; ++j)
                dst[j * 16] = acc[i][j][r] + bv;
        }
    }
}

// ---------------------------------------------------------------------------
// big GEMM fallback (X split in-kernel, no XT needed) — 3-product, reads
// P hi/lo planes (the no-XT chain path still writes them at the final step)
// ---------------------------------------------------------------------------
#define PADK 40

__launch_bounds__(256)
__global__ void big_gemm_k(const unsigned short* __restrict__ Ahi_g,
                           const unsigned short* __restrict__ Alo_g,
                           const float* __restrict__ X, float* __restrict__ C,
                           const float* __restrict__ bias)
{
    __shared__ unsigned short Ahi[128][PADK], Alo[128][PADK];
    __shared__ unsigned short Bhi[128][PADK], Blo[128][PADK];

    const int tid = threadIdx.x;
    const int wave = tid >> 6;
    const int lane = tid & 63;
    const int wr = (wave >> 1) * 64;
    const int wc = (wave & 1) * 64;
    const int m0 = blockIdx.y * 128;
    const int n0 = blockIdx.x * 128;
    const int lg = lane >> 4;
    const int lm = lane & 15;

    f32x4 acc[4][4] = {};

    for (int k0 = 0; k0 < H; k0 += 32) {
        #pragma unroll
        for (int a2 = 0; a2 < 2; ++a2) {
            const int id = tid + a2 * 256;
            const int row = id >> 2;
            const int ko = id & 3;
            const size_t g = (size_t)(m0 + row) * H + k0 + ko * 8;
            *(bf16x8*)&Ahi[row][ko * 8] = *(const bf16x8*)&Ahi_g[g];
            *(bf16x8*)&Alo[row][ko * 8] = *(const bf16x8*)&Alo_g[g];
        }
        #pragma unroll
        for (int a2 = 0; a2 < 2; ++a2) {
            const int id = tid + a2 * 256;
            const int n = id & 127;
            const int ko = id >> 7;
            const float* src = &X[(size_t)(k0 + ko * 8) * BATCH + n0 + n];
            bf16x8 bh, bl;
            #pragma unroll
            for (int i = 0; i < 8; ++i) {
                unsigned short hh, ll;
                split2(src[(size_t)i * BATCH], hh, ll);
                bh[i] = (short)hh;
                bl[i] = (short)ll;
            }
            *(bf16x8*)&Bhi[n][ko * 8] = bh;
            *(bf16x8*)&Blo[n][ko * 8] = bl;
        }
        __syncthreads();

        bf16x8 ah[4], al[4], bh[4], bl[4];
        #pragma unroll
        for (int i = 0; i < 4; ++i) {
            const int m = wr + i * 16 + lm;
            ah[i] = *(const bf16x8*)&Ahi[m][lg * 8];
            al[i] = *(const bf16x8*)&Alo[m][lg * 8];
            const int n = wc + i * 16 + lm;
            bh[i] = *(const bf16x8*)&Bhi[n][lg * 8];
            bl[i] = *(const bf16x8*)&Blo[n][lg * 8];
        }
        #pragma unroll
        for (int i = 0; i < 4; ++i)
            #pragma unroll
            for (int j = 0; j < 4; ++j) {
                acc[i][j] = __builtin_amdgcn_mfma_f32_16x16x32_bf16(ah[i], bh[j], acc[i][j], 0, 0, 0);
                acc[i][j] = __builtin_amdgcn_mfma_f32_16x16x32_bf16(ah[i], bl[j], acc[i][j], 0, 0, 0);
                acc[i][j] = __builtin_amdgcn_mfma_f32_16x16x32_bf16(al[i], bh[j], acc[i][j], 0, 0, 0);
            }
        __syncthreads();
    }

    #pragma unroll
    for (int i = 0; i < 4; ++i) {
        const int rowb = m0 + wr + i * 16 + lg * 4;
        #pragma unroll
        for (int r = 0; r < 4; ++r) {
            const float bv = bias[rowb + r];
            float* dst = &C[(size_t)(rowb + r) * BATCH + n0 + wc + lm];
            #pragma unroll
            for (int j = 0; j < 4; ++j)
                dst[j * 16] = acc[i][j][r] + bv;
        }
    }
}

// ---------------------------------------------------------------------------
// host-side launcher
// ---------------------------------------------------------------------------
extern "C" void kernel_launch(void* const* d_in, const int* in_sizes, int n_in,
                              void* d_out, int out_size, void* d_ws, size_t ws_size,
                              hipStream_t stream)
{
    const float* x0 = (const float*)d_in[0];
    const float* t0 = (const float*)d_in[1];
    const float* t1 = (const float*)d_in[2];
    const float* W  = (const float*)d_in[3];
    const float* bb = (const float*)d_in[4];
    float* out = (float*)d_out;

    // ws layout: A planes {hi,lo,hiT,loT} (8MB) | cv,v0,v1 | @16MB: XhiT (16MB)
    unsigned short* Aplanes = (unsigned short*)d_ws;
    unsigned short* Ahi  = Aplanes;
    unsigned short* Alo  = Aplanes + HH;
    float* cv = (float*)(Aplanes + 4 * HH);
    float* v0 = cv + H;
    float* v1 = v0 + H;

    const size_t xtoff = (size_t)16 * 1024 * 1024;
    const bool useXT = ws_size >= xtoff + (size_t)BATCH * H * sizeof(unsigned short);
    unsigned short* XhiT = (unsigned short*)((char*)d_ws + xtoff);

    // d_out scratch: two ping-pong plane-sets {hi,lo,hiT,loT}, 8MB each (16MB),
    // fully overwritten by the final 32MB C write.
    unsigned short* PA = (unsigned short*)d_out;
    unsigned short* PB = PA + (size_t)4 * HH;

    setup_k<<<256, 256, 0, stream>>>(W, bb, t0, t1, Aplanes, cv, v0);

    // addition chain 1 -> 2 -> 3 -> 6 -> 12 -> 24 -> 25 -> 50
    const int seq[7] = {0, 1, 0, 0, 0, 1, 0};   // 0=SQ, 1=MUL
    unsigned short* cur = Ahi;                  // P_1 = A (4 consecutive planes)
    float* vin = v0;
    float* vout = v1;
    for (int s = 0; s < 7; ++s) {
        const unsigned short* L  = seq[s] ? Ahi : cur;
        const unsigned short* Ll = seq[s] ? Alo : cur + HH;
        const float* addv = seq[s] ? cv : vin;
        if (s == 0) {
            unsigned short* nxt = PA;
            if (useXT) {
                chain_fused_k<true, true, false><<<2320, 512, 0, stream>>>(
                    L, Ll, cur + 2 * HH, cur + 3 * HH,
                    nxt, nxt + HH, nxt + 2 * HH, nxt + 3 * HH,
                    vin, addv, vout, x0, XhiT);
            } else {
                chain_fused_k<true, false, false><<<272, 512, 0, stream>>>(
                    L, Ll, cur + 2 * HH, cur + 3 * HH,
                    nxt, nxt + HH, nxt + 2 * HH, nxt + 3 * HH,
                    vin, addv, vout, nullptr, nullptr);
            }
            cur = nxt;
        } else if (s < 6) {
            unsigned short* nxt = (s & 1) ? PB : PA;
            chain_fused_k<true, false, false><<<272, 512, 0, stream>>>(
                L, Ll, cur + 2 * HH, cur + 3 * HH,
                nxt, nxt + HH, nxt + 2 * HH, nxt + 3 * HH,
                vin, addv, vout, nullptr, nullptr);
            cur = nxt;
        } else if (useXT) {
            // final step: write ONLY the rounded single plane Pr -> Ahi
            // (A planes dead; big_gemm1 is the sole consumer of P_50)
            chain_fused_k<false, false, true><<<272, 512, 0, stream>>>(
                L, Ll, cur + 2 * HH, cur + 3 * HH,
                Ahi, nullptr, nullptr, nullptr,
                vin, addv, vout, nullptr, nullptr);
            cur = Ahi;
        } else {
            // fallback path: final step writes hi/lo planes for big_gemm_k
            chain_fused_k<false, false, false><<<272, 512, 0, stream>>>(
                L, Ll, cur + 2 * HH, cur + 3 * HH,
                Ahi, Alo, nullptr, nullptr,
                vin, addv, vout, nullptr, nullptr);
            cur = Ahi;
        }
        float* tv = vin; vin = vout; vout = tv;
    }
    // cur = P_50 (Pr single plane in Ahi if useXT); vin = v_50

    if (useXT) {
        big_gemm1_k<<<512, 256, 0, stream>>>(Ahi, XhiT, out, vin);
    } else {
        big_gemm_k<<<dim3(BATCH / 128, H / 128), 256, 0, stream>>>(
            Ahi, Alo, x0, out, vin);
    }
}

// Round 13
// 150.801 us; speedup vs baseline: 1.1060x; 1.0424x over previous
//
#include <hip/hip_runtime.h>

#define H 1024
#define HH (H * H)
#define BATCH 8192
#define NSTEPS 50

typedef __attribute__((ext_vector_type(8))) short bf16x8;
typedef __attribute__((ext_vector_type(4))) float f32x4;

// ---------------------------------------------------------------------------
// helpers
// ---------------------------------------------------------------------------
__device__ __forceinline__ void split2(float a, unsigned short& h, unsigned short& l)
{
    unsigned u = __float_as_uint(a);
    float r = a - __uint_as_float(u & 0xFFFF0000u);   // exact residual
    h = (unsigned short)(u >> 16);                    // truncated bf16
    l = (unsigned short)((__float_as_uint(r) + 0x8000u) >> 16); // rounded residual
}
__device__ __forceinline__ unsigned short rnd_bf16(float a)
{
    return (unsigned short)((__float_as_uint(a) + 0x8000u) >> 16);  // round-half-up
}
__device__ __forceinline__ float bf2f(unsigned short s)
{
    return __uint_as_float(((unsigned)s) << 16);
}
__device__ __forceinline__ void gload16(const void* g, void* l)
{
    __builtin_amdgcn_global_load_lds(
        (const __attribute__((address_space(1))) void*)g,
        (__attribute__((address_space(3))) void*)l, 16, 0, 0);
}
#define VMCNT(n) asm volatile("s_waitcnt vmcnt(" #n ")" ::: "memory")
#define RBAR() do { __builtin_amdgcn_s_barrier(); __builtin_amdgcn_sched_barrier(0); } while (0)

// ---------------------------------------------------------------------------
// setup: A = I + h*W as bf16 hi/lo planes, normal + transposed; cv/v0 = h*b.
// ---------------------------------------------------------------------------
__global__ void setup_k(const float* __restrict__ W, const float* __restrict__ bvec,
                        const float* __restrict__ t0, const float* __restrict__ t1,
                        unsigned short* __restrict__ Aplanes,
                        float* __restrict__ cv, float* __restrict__ v0)
{
    __shared__ unsigned short th[64][68], tl[64][68];
    const float h = (t1[0] - t0[0]) / (float)NSTEPS;
    const int bid = blockIdx.x, tid = threadIdx.x;
    const int rb = (bid >> 4) * 64, cb = (bid & 15) * 64;
    const int row = tid >> 2, c16 = (tid & 3) * 16;

    unsigned short* Ahi  = Aplanes;
    unsigned short* Alo  = Aplanes + HH;
    unsigned short* AhiT = Aplanes + 2 * HH;
    unsigned short* AloT = Aplanes + 3 * HH;

    {
        const float* wsrc = &W[(size_t)(rb + row) * H + cb + c16];
        bf16x8 hv[2], lv[2];
        #pragma unroll
        for (int q = 0; q < 16; ++q) {
            const float a = h * wsrc[q] + ((rb + row) == (cb + c16 + q) ? 1.0f : 0.0f);
            unsigned short hh, ll;
            split2(a, hh, ll);
            hv[q >> 3][q & 7] = (short)hh;
            lv[q >> 3][q & 7] = (short)ll;
            th[row][c16 + q] = hh;
            tl[row][c16 + q] = ll;
        }
        *(bf16x8*)&Ahi[(size_t)(rb + row) * H + cb + c16] = hv[0];
        *(bf16x8*)&Ahi[(size_t)(rb + row) * H + cb + c16 + 8] = hv[1];
        *(bf16x8*)&Alo[(size_t)(rb + row) * H + cb + c16] = lv[0];
        *(bf16x8*)&Alo[(size_t)(rb + row) * H + cb + c16 + 8] = lv[1];
    }
    __syncthreads();
    {
        bf16x8 hv[2], lv[2];
        #pragma unroll
        for (int q = 0; q < 16; ++q) {
            hv[q >> 3][q & 7] = (short)th[c16 + q][row];
            lv[q >> 3][q & 7] = (short)tl[c16 + q][row];
        }
        *(bf16x8*)&AhiT[(size_t)(cb + row) * H + rb + c16] = hv[0];
        *(bf16x8*)&AhiT[(size_t)(cb + row) * H + rb + c16 + 8] = hv[1];
        *(bf16x8*)&AloT[(size_t)(cb + row) * H + rb + c16] = lv[0];
        *(bf16x8*)&AloT[(size_t)(cb + row) * H + rb + c16 + 8] = lv[1];
    }
    if (bid == 0) {
        #pragma unroll
        for (int rep = 0; rep < 4; ++rep) {
            const int i = tid + rep * 256;
            const float v = h * bvec[i];
            cv[i] = v; v0[i] = v;
        }
    }
}

// ---------------------------------------------------------------------------
// fused chain step (round-10 proven structure): 512 threads.
//  blocks [0,256):   Q = L * R  (64x64 tile, 8 waves, in-block split-K=2,
//                    2-buffer __syncthreads staging via gload_lds, 3-product)
//  blocks [256,272): vout = addv + (Lhi+Llo) * vin
//  blocks [272,2320) (DO_X only): X fp32 -> transposed bf16 plane XhiT
// Epilogue planes written per consumer needs:
//   WRITE_N: normal hi/lo planes (skipped when consumer is a MUL step)
//   WRITE_T: transposed hi/lo planes
//   PR:      single rounded bf16 plane only (final step -> bf16 big GEMM)
// ---------------------------------------------------------------------------
template<bool WRITE_N, bool WRITE_T, bool DO_X, bool PR>
__launch_bounds__(512)
__global__ void chain_fused_k(const unsigned short* __restrict__ Lhi,
                              const unsigned short* __restrict__ Llo,
                              const unsigned short* __restrict__ RThi,
                              const unsigned short* __restrict__ RTlo,
                              unsigned short* __restrict__ Qhi,
                              unsigned short* __restrict__ Qlo,
                              unsigned short* __restrict__ QhiT,
                              unsigned short* __restrict__ QloT,
                              const float* __restrict__ vin,
                              const float* __restrict__ addv,
                              float* __restrict__ vout,
                              const float* __restrict__ X,
                              unsigned short* __restrict__ XhiT)
{
    __shared__ unsigned short sA[2][2][2][64][32];  // [dbuf][khalf][plane][row][k] 32KB
    __shared__ unsigned short sB[2][2][2][64][32];  // 32KB

    const int tid = threadIdx.x;
    const int bid = blockIdx.x;
    const int wave = tid >> 6, lane = tid & 63;

    if (DO_X && bid >= 272) {
        // ---- X transpose blocks: fp32 -> rounded bf16, transposed ----
        float (*ts)[65] = (float(*)[65])&sA[0][0][0][0][0];   // 16.6KB overlay
        const int tile = bid - 272;                            // 0..2047
        const int n0x = (tile >> 4) * 64, k0x = (tile & 15) * 64;
        #pragma unroll
        for (int p = 0; p < 2; ++p) {
            const int kr = p * 32 + (tid >> 4);     // k-local
            const int c4 = (tid & 15) * 4;          // n-local
            const float4 v = *(const float4*)&X[(size_t)(k0x + kr) * BATCH + n0x + c4];
            ts[kr][c4 + 0] = v.x; ts[kr][c4 + 1] = v.y;
            ts[kr][c4 + 2] = v.z; ts[kr][c4 + 3] = v.w;
        }
        __syncthreads();
        {
            const int n = tid >> 3;                 // n-local 0..63
            const int kc = (tid & 7) * 8;           // k-local chunk
            bf16x8 hv;
            #pragma unroll
            for (int q = 0; q < 8; ++q)
                hv[q] = (short)rnd_bf16(ts[kc + q][n]);
            *(bf16x8*)&XhiT[(size_t)(n0x + n) * H + k0x + kc] = hv;
        }
        return;
    }

    if (bid >= 256) {
        // ---- matvec blocks ----
        const int rowbase = (bid - 256) * 64 + wave * 8;
        const float4* xq = (const float4*)vin + lane * 4;
        float4 xv[4];
        #pragma unroll
        for (int q = 0; q < 4; ++q) xv[q] = xq[q];
        #pragma unroll
        for (int rr = 0; rr < 8; ++rr) {
            const int row = rowbase + rr;
            const unsigned short* mh = Lhi + (size_t)row * H + lane * 16;
            const unsigned short* ml = Llo + (size_t)row * H + lane * 16;
            bf16x8 h0 = *(const bf16x8*)&mh[0];
            bf16x8 h1 = *(const bf16x8*)&mh[8];
            bf16x8 l0 = *(const bf16x8*)&ml[0];
            bf16x8 l1 = *(const bf16x8*)&ml[8];
            float s = 0.0f;
            #pragma unroll
            for (int q = 0; q < 8; ++q) {
                const float m0v = bf2f((unsigned short)h0[q]) + bf2f((unsigned short)l0[q]);
                const float m1v = bf2f((unsigned short)h1[q]) + bf2f((unsigned short)l1[q]);
                const float* xf = (const float*)xv;
                s = fmaf(m0v, xf[q], s);
                s = fmaf(m1v, xf[8 + q], s);
            }
            #pragma unroll
            for (int off = 32; off; off >>= 1)
                s += __shfl_down(s, off, 64);
            if (lane == 0) vout[row] = addv[row] + s;
        }
        return;
    }

    // ---- GEMM blocks ----
    const int lg = lane >> 4, lm = lane & 15;
    const int half = wave >> 2;               // k-half owner
    const int wq = wave & 3;
    const int wr2 = (wq >> 1) * 32, wc2 = (wq & 1) * 32;
    // 2D patch per XCD
    const int xcd = bid & 7;
    const int idx0 = bid >> 3;
    const int mt = (xcd >> 1) * 4 + (idx0 & 3);
    const int nt = (xcd & 1) * 8 + (idx0 >> 2);
    const int m0 = mt * 64, n0 = nt * 64;

    f32x4 acc[2][2] = {};

    #define CSTAGE(tt, b) do {                                                   \
        _Pragma("unroll")                                                        \
        for (int it = 0; it < 4; ++it) {                                         \
            const int idx = tid + it * 512;                                      \
            const int mat = idx >> 10, kh = (idx >> 9) & 1;                      \
            const int plane = (idx >> 8) & 1;                                    \
            const int row = (idx >> 2) & 63, kc = idx & 3;                       \
            const int ks = kc ^ ((row >> 1) & 3);                                \
            const unsigned short* g = mat ? (plane ? RTlo : RThi)                \
                                          : (plane ? Llo : Lhi);                 \
            const int rb = mat ? n0 : m0;                                        \
            unsigned short* d = mat ? &sB[b][kh][plane][row][kc * 8]             \
                                    : &sA[b][kh][plane][row][kc * 8];            \
            gload16(g + (size_t)(rb + row) * H + kh * 512 + (tt) * 32 + ks * 8, d); \
        }                                                                        \
    } while (0)

    CSTAGE(0, 0);
    __syncthreads();
    int buf = 0;
    for (int t = 0; t < 16; ++t) {
        if (t + 1 < 16) CSTAGE(t + 1, buf ^ 1);
        bf16x8 ah[2], al[2], bh[2], bl[2];
        #pragma unroll
        for (int i = 0; i < 2; ++i) {
            const int row = wr2 + i * 16 + lm;
            const int sl = lg ^ ((row >> 1) & 3);
            ah[i] = *(const bf16x8*)&sA[buf][half][0][row][sl * 8];
            al[i] = *(const bf16x8*)&sA[buf][half][1][row][sl * 8];
            const int rn = wc2 + i * 16 + lm;
            const int sn = lg ^ ((rn >> 1) & 3);
            bh[i] = *(const bf16x8*)&sB[buf][half][0][rn][sn * 8];
            bl[i] = *(const bf16x8*)&sB[buf][half][1][rn][sn * 8];
        }
        #pragma unroll
        for (int i = 0; i < 2; ++i)
            #pragma unroll
            for (int j = 0; j < 2; ++j) {
                acc[i][j] = __builtin_amdgcn_mfma_f32_16x16x32_bf16(ah[i], bh[j], acc[i][j], 0, 0, 0);
                acc[i][j] = __builtin_amdgcn_mfma_f32_16x16x32_bf16(ah[i], bl[j], acc[i][j], 0, 0, 0);
                acc[i][j] = __builtin_amdgcn_mfma_f32_16x16x32_bf16(al[i], bh[j], acc[i][j], 0, 0, 0);
            }
        __syncthreads();
        buf ^= 1;
    }
    #undef CSTAGE

    // cross-half reduce via LDS (stride 17 floats)
    float* red = (float*)&sA[0][0][0][0][0];
    const int ridx = wq * 64 + lane;
    if (half == 1) {
        float* dst = red + (size_t)ridx * 17;
        #pragma unroll
        for (int i = 0; i < 2; ++i)
            #pragma unroll
            for (int j = 0; j < 2; ++j)
                *(f32x4*)&dst[(i * 2 + j) * 4] = acc[i][j];
    }
    __syncthreads();
    if (half == 0) {
        const float* src = red + (size_t)ridx * 17;
        #pragma unroll
        for (int i = 0; i < 2; ++i)
            #pragma unroll
            for (int j = 0; j < 2; ++j) {
                const f32x4 p = *(const f32x4*)&src[(i * 2 + j) * 4];
                acc[i][j] += p;
            }
        #pragma unroll
        for (int i = 0; i < 2; ++i) {
            const int row0 = m0 + wr2 + i * 16 + lg * 4;
            #pragma unroll
            for (int j = 0; j < 2; ++j) {
                const int col = n0 + wc2 + j * 16 + lm;
                if (PR) {
                    // final step: single rounded bf16 plane (big GEMM input)
                    #pragma unroll
                    for (int r = 0; r < 4; ++r)
                        Qhi[(size_t)(row0 + r) * H + col] = rnd_bf16(acc[i][j][r]);
                } else {
                    unsigned short hs[4], ls[4];
                    #pragma unroll
                    for (int r = 0; r < 4; ++r) {
                        split2(acc[i][j][r], hs[r], ls[r]);
                        if (WRITE_N) {
                            Qhi[(size_t)(row0 + r) * H + col] = hs[r];
                            Qlo[(size_t)(row0 + r) * H + col] = ls[r];
                        }
                    }
                    if (WRITE_T) {
                        ushort4 th, tl;
                        th.x = hs[0]; th.y = hs[1]; th.z = hs[2]; th.w = hs[3];
                        tl.x = ls[0]; tl.y = ls[1]; tl.z = ls[2]; tl.w = ls[3];
                        *(ushort4*)&QhiT[(size_t)col * H + row0] = th;
                        *(ushort4*)&QloT[(size_t)col * H + row0] = tl;
                    }
                }
            }
        }
    }
}

// ---------------------------------------------------------------------------
// big GEMM, bf16 x bf16 (1 MFMA per fragment): C = Pr * Xh + bias.
// 128x128 tile, 256 threads (4 waves, 64x64 each), BK=32, 3-buffer
// counted-vmcnt pipe (round-5/6-proven single-barrier structure):
// read frags(t) -> issue stage(t+2) -> MFMA -> VMCNT(2) -> barrier.
// grid 512 = 2 blocks/CU, 48KB LDS. XCD swizzle: 8 n-tiles per XCD.
// ---------------------------------------------------------------------------
__launch_bounds__(256)
__global__ void big_gemm1_k(const unsigned short* __restrict__ Pr,
                            const unsigned short* __restrict__ XhiT,
                            float* __restrict__ C, const float* __restrict__ bias)
{
    __shared__ unsigned short sA[3][128][32];   // 24KB
    __shared__ unsigned short sB[3][128][32];   // 24KB

    const int tid = threadIdx.x;
    const int wave = tid >> 6, lane = tid & 63;
    const int lg = lane >> 4, lm = lane & 15;
    const int wr2 = (wave >> 1) * 64;    // wave tile 64x64
    const int wc2 = (wave & 1) * 64;
    const int bid = blockIdx.x;
    const int l = bid >> 3;              // 0..63
    const int m0 = (l & 7) * 128;
    const int n0 = ((bid & 7) * 8 + (l >> 3)) * 128;

    f32x4 acc[4][4] = {};

    #define BSTAGE(tt, b) do {                                                   \
        _Pragma("unroll")                                                        \
        for (int it = 0; it < 2; ++it) {                                         \
            const int idx = tid + it * 256;                                      \
            const int row = idx >> 2, kc = idx & 3;                              \
            const int ks = kc ^ ((row >> 1) & 3);                                \
            const size_t go = (size_t)(tt) * 32 + ks * 8;                        \
            gload16(Pr   + (size_t)(m0 + row) * H + go, &sA[b][row][kc * 8]);    \
            gload16(XhiT + (size_t)(n0 + row) * H + go, &sB[b][row][kc * 8]);    \
        }                                                                        \
    } while (0)

    BSTAGE(0, 0);
    BSTAGE(1, 1);
    VMCNT(2);
    RBAR();

    #pragma unroll
    for (int t = 0; t < 32; ++t) {
        const int b = t % 3;
        bf16x8 ah[4], bh[4];
        #pragma unroll
        for (int i = 0; i < 4; ++i) {
            const int row = wr2 + i * 16 + lm;
            const int sl = lg ^ ((row >> 1) & 3);
            ah[i] = *(const bf16x8*)&sA[b][row][sl * 8];
            const int rn = wc2 + i * 16 + lm;
            const int sn = lg ^ ((rn >> 1) & 3);
            bh[i] = *(const bf16x8*)&sB[b][rn][sn * 8];
        }
        if (t + 2 < 32) BSTAGE(t + 2, (t + 2) % 3);
        __builtin_amdgcn_s_setprio(1);
        #pragma unroll
        for (int i = 0; i < 4; ++i)
            #pragma unroll
            for (int j = 0; j < 4; ++j)
                acc[i][j] = __builtin_amdgcn_mfma_f32_16x16x32_bf16(ah[i], bh[j], acc[i][j], 0, 0, 0);
        __builtin_amdgcn_s_setprio(0);
        if (t < 30) VMCNT(2);        // stage t+1 complete; t+2 may stay in flight
        else if (t == 30) VMCNT(0);
        if (t < 31) RBAR();
    }
    #undef BSTAGE

    #pragma unroll
    for (int i = 0; i < 4; ++i) {
        const int row0 = m0 + wr2 + i * 16 + lg * 4;
        #pragma unroll
        for (int r = 0; r < 4; ++r) {
            const float bv = bias[row0 + r];
            float* dst = &C[(size_t)(row0 + r) * BATCH + n0 + wc2 + lm];
            #pragma unroll
            for (int j = 0; j < 4; ++j)
                dst[j * 16] = acc[i][j][r] + bv;
        }
    }
}

// ---------------------------------------------------------------------------
// big GEMM fallback (X split in-kernel, no XT needed) — 3-product, reads
// P hi/lo planes (the no-XT chain path still writes them at the final step)
// ---------------------------------------------------------------------------
#define PADK 40

__launch_bounds__(256)
__global__ void big_gemm_k(const unsigned short* __restrict__ Ahi_g,
                           const unsigned short* __restrict__ Alo_g,
                           const float* __restrict__ X, float* __restrict__ C,
                           const float* __restrict__ bias)
{
    __shared__ unsigned short Ahi[128][PADK], Alo[128][PADK];
    __shared__ unsigned short Bhi[128][PADK], Blo[128][PADK];

    const int tid = threadIdx.x;
    const int wave = tid >> 6;
    const int lane = tid & 63;
    const int wr = (wave >> 1) * 64;
    const int wc = (wave & 1) * 64;
    const int m0 = blockIdx.y * 128;
    const int n0 = blockIdx.x * 128;
    const int lg = lane >> 4;
    const int lm = lane & 15;

    f32x4 acc[4][4] = {};

    for (int k0 = 0; k0 < H; k0 += 32) {
        #pragma unroll
        for (int a2 = 0; a2 < 2; ++a2) {
            const int id = tid + a2 * 256;
            const int row = id >> 2;
            const int ko = id & 3;
            const size_t g = (size_t)(m0 + row) * H + k0 + ko * 8;
            *(bf16x8*)&Ahi[row][ko * 8] = *(const bf16x8*)&Ahi_g[g];
            *(bf16x8*)&Alo[row][ko * 8] = *(const bf16x8*)&Alo_g[g];
        }
        #pragma unroll
        for (int a2 = 0; a2 < 2; ++a2) {
            const int id = tid + a2 * 256;
            const int n = id & 127;
            const int ko = id >> 7;
            const float* src = &X[(size_t)(k0 + ko * 8) * BATCH + n0 + n];
            bf16x8 bh, bl;
            #pragma unroll
            for (int i = 0; i < 8; ++i) {
                unsigned short hh, ll;
                split2(src[(size_t)i * BATCH], hh, ll);
                bh[i] = (short)hh;
                bl[i] = (short)ll;
            }
            *(bf16x8*)&Bhi[n][ko * 8] = bh;
            *(bf16x8*)&Blo[n][ko * 8] = bl;
        }
        __syncthreads();

        bf16x8 ah[4], al[4], bh[4], bl[4];
        #pragma unroll
        for (int i = 0; i < 4; ++i) {
            const int m = wr + i * 16 + lm;
            ah[i] = *(const bf16x8*)&Ahi[m][lg * 8];
            al[i] = *(const bf16x8*)&Alo[m][lg * 8];
            const int n = wc + i * 16 + lm;
            bh[i] = *(const bf16x8*)&Bhi[n][lg * 8];
            bl[i] = *(const bf16x8*)&Blo[n][lg * 8];
        }
        #pragma unroll
        for (int i = 0; i < 4; ++i)
            #pragma unroll
            for (int j = 0; j < 4; ++j) {
                acc[i][j] = __builtin_amdgcn_mfma_f32_16x16x32_bf16(ah[i], bh[j], acc[i][j], 0, 0, 0);
                acc[i][j] = __builtin_amdgcn_mfma_f32_16x16x32_bf16(ah[i], bl[j], acc[i][j], 0, 0, 0);
                acc[i][j] = __builtin_amdgcn_mfma_f32_16x16x32_bf16(al[i], bh[j], acc[i][j], 0, 0, 0);
            }
        __syncthreads();
    }

    #pragma unroll
    for (int i = 0; i < 4; ++i) {
        const int rowb = m0 + wr + i * 16 + lg * 4;
        #pragma unroll
        for (int r = 0; r < 4; ++r) {
            const float bv = bias[rowb + r];
            float* dst = &C[(size_t)(rowb + r) * BATCH + n0 + wc + lm];
            #pragma unroll
            for (int j = 0; j < 4; ++j)
                dst[j * 16] = acc[i][j][r] + bv;
        }
    }
}

// ---------------------------------------------------------------------------
// host-side launcher
// ---------------------------------------------------------------------------
extern "C" void kernel_launch(void* const* d_in, const int* in_sizes, int n_in,
                              void* d_out, int out_size, void* d_ws, size_t ws_size,
                              hipStream_t stream)
{
    const float* x0 = (const float*)d_in[0];
    const float* t0 = (const float*)d_in[1];
    const float* t1 = (const float*)d_in[2];
    const float* W  = (const float*)d_in[3];
    const float* bb = (const float*)d_in[4];
    float* out = (float*)d_out;

    // ws layout: A planes {hi,lo,hiT,loT} (8MB) | cv,v0,v1 | @16MB: XhiT (16MB)
    unsigned short* Aplanes = (unsigned short*)d_ws;
    unsigned short* Ahi  = Aplanes;
    unsigned short* Alo  = Aplanes + HH;
    float* cv = (float*)(Aplanes + 4 * HH);
    float* v0 = cv + H;
    float* v1 = v0 + H;

    const size_t xtoff = (size_t)16 * 1024 * 1024;
    const bool useXT = ws_size >= xtoff + (size_t)BATCH * H * sizeof(unsigned short);
    unsigned short* XhiT = (unsigned short*)((char*)d_ws + xtoff);

    // d_out scratch: two ping-pong plane-sets {hi,lo,hiT,loT}, 8MB each (16MB),
    // fully overwritten by the final 32MB C write.
    unsigned short* PA = (unsigned short*)d_out;
    unsigned short* PB = PA + (size_t)4 * HH;

    setup_k<<<256, 256, 0, stream>>>(W, bb, t0, t1, Aplanes, cv, v0);

    // addition chain 1 -> 2 -> 3 -> 6 -> 12 -> 24 -> 25 -> 50
    // seq: s=0 SQ, 1 MUL, 2 SQ, 3 SQ, 4 SQ, 5 MUL, 6 SQ
    // Consumer of step s's output determines planes written:
    //   s=0 -> s=1 (MUL, L=A): T planes only
    //   s=4 -> s=5 (MUL, L=A): T planes only
    //   others: normal + T; s=6: rounded single plane (big GEMM)
    const int seq[7] = {0, 1, 0, 0, 0, 1, 0};
    unsigned short* cur = Ahi;                  // P_1 = A (4 consecutive planes)
    float* vin = v0;
    float* vout = v1;
    for (int s = 0; s < 7; ++s) {
        const unsigned short* L  = seq[s] ? Ahi : cur;
        const unsigned short* Ll = seq[s] ? Alo : cur + HH;
        const float* addv = seq[s] ? cv : vin;
        if (s == 0) {
            unsigned short* nxt = PA;
            if (useXT) {
                chain_fused_k<false, true, true, false><<<2320, 512, 0, stream>>>(
                    L, Ll, cur + 2 * HH, cur + 3 * HH,
                    nxt, nxt + HH, nxt + 2 * HH, nxt + 3 * HH,
                    vin, addv, vout, x0, XhiT);
            } else {
                chain_fused_k<false, true, false, false><<<272, 512, 0, stream>>>(
                    L, Ll, cur + 2 * HH, cur + 3 * HH,
                    nxt, nxt + HH, nxt + 2 * HH, nxt + 3 * HH,
                    vin, addv, vout, nullptr, nullptr);
            }
            cur = nxt;
        } else if (s == 4) {
            unsigned short* nxt = PA;   // s=4 even -> PA
            chain_fused_k<false, true, false, false><<<272, 512, 0, stream>>>(
                L, Ll, cur + 2 * HH, cur + 3 * HH,
                nxt, nxt + HH, nxt + 2 * HH, nxt + 3 * HH,
                vin, addv, vout, nullptr, nullptr);
            cur = nxt;
        } else if (s < 6) {
            unsigned short* nxt = (s & 1) ? PB : PA;
            chain_fused_k<true, true, false, false><<<272, 512, 0, stream>>>(
                L, Ll, cur + 2 * HH, cur + 3 * HH,
                nxt, nxt + HH, nxt + 2 * HH, nxt + 3 * HH,
                vin, addv, vout, nullptr, nullptr);
            cur = nxt;
        } else if (useXT) {
            // final step: write ONLY the rounded single plane Pr -> Ahi
            chain_fused_k<false, false, false, true><<<272, 512, 0, stream>>>(
                L, Ll, cur + 2 * HH, cur + 3 * HH,
                Ahi, nullptr, nullptr, nullptr,
                vin, addv, vout, nullptr, nullptr);
            cur = Ahi;
        } else {
            // fallback path: final step writes hi/lo planes for big_gemm_k
            chain_fused_k<true, false, false, false><<<272, 512, 0, stream>>>(
                L, Ll, cur + 2 * HH, cur + 3 * HH,
                Ahi, Alo, nullptr, nullptr,
                vin, addv, vout, nullptr, nullptr);
            cur = Ahi;
        }
        float* tv = vin; vin = vout; vout = tv;
    }
    // cur = P_50 (Pr single plane in Ahi if useXT); vin = v_50

    if (useXT) {
        big_gemm1_k<<<512, 256, 0, stream>>>(Ahi, XhiT, out, vin);
    } else {
        big_gemm_k<<<dim3(BATCH / 128, H / 128), 256, 0, stream>>>(
            Ahi, Alo, x0, out, vin);
    }
}

// Round 14
// 133.391 us; speedup vs baseline: 1.2503x; 1.1305x over previous
//
#include <hip/hip_runtime.h>

#define H 1024
#define HH (H * H)
#define BATCH 8192
#define NSTEPS 50

typedef __attribute__((ext_vector_type(8))) short bf16x8;
typedef __attribute__((ext_vector_type(4))) float f32x4;

// ---------------------------------------------------------------------------
// helpers
// ---------------------------------------------------------------------------
__device__ __forceinline__ void split2(float a, unsigned short& h, unsigned short& l)
{
    unsigned u = __float_as_uint(a);
    float r = a - __uint_as_float(u & 0xFFFF0000u);   // exact residual
    h = (unsigned short)(u >> 16);                    // truncated bf16
    l = (unsigned short)((__float_as_uint(r) + 0x8000u) >> 16); // rounded residual
}
__device__ __forceinline__ unsigned short rnd_bf16(float a)
{
    return (unsigned short)((__float_as_uint(a) + 0x8000u) >> 16);  // round-half-up
}
__device__ __forceinline__ float bf2f(unsigned short s)
{
    return __uint_as_float(((unsigned)s) << 16);
}
__device__ __forceinline__ void gload16(const void* g, void* l)
{
    __builtin_amdgcn_global_load_lds(
        (const __attribute__((address_space(1))) void*)g,
        (__attribute__((address_space(3))) void*)l, 16, 0, 0);
}
#define VMCNT(n) asm volatile("s_waitcnt vmcnt(" #n ")" ::: "memory")
#define RBAR() do { __builtin_amdgcn_s_barrier(); __builtin_amdgcn_sched_barrier(0); } while (0)

// ---------------------------------------------------------------------------
// setup: A = I + h*W as bf16 hi/lo planes, normal + transposed; cv/v0 = h*b.
// ---------------------------------------------------------------------------
__global__ void setup_k(const float* __restrict__ W, const float* __restrict__ bvec,
                        const float* __restrict__ t0, const float* __restrict__ t1,
                        unsigned short* __restrict__ Aplanes,
                        float* __restrict__ cv, float* __restrict__ v0)
{
    __shared__ unsigned short th[64][68], tl[64][68];
    const float h = (t1[0] - t0[0]) / (float)NSTEPS;
    const int bid = blockIdx.x, tid = threadIdx.x;
    const int rb = (bid >> 4) * 64, cb = (bid & 15) * 64;
    const int row = tid >> 2, c16 = (tid & 3) * 16;

    unsigned short* Ahi  = Aplanes;
    unsigned short* Alo  = Aplanes + HH;
    unsigned short* AhiT = Aplanes + 2 * HH;
    unsigned short* AloT = Aplanes + 3 * HH;

    {
        const float* wsrc = &W[(size_t)(rb + row) * H + cb + c16];
        bf16x8 hv[2], lv[2];
        #pragma unroll
        for (int q = 0; q < 16; ++q) {
            const float a = h * wsrc[q] + ((rb + row) == (cb + c16 + q) ? 1.0f : 0.0f);
            unsigned short hh, ll;
            split2(a, hh, ll);
            hv[q >> 3][q & 7] = (short)hh;
            lv[q >> 3][q & 7] = (short)ll;
            th[row][c16 + q] = hh;
            tl[row][c16 + q] = ll;
        }
        *(bf16x8*)&Ahi[(size_t)(rb + row) * H + cb + c16] = hv[0];
        *(bf16x8*)&Ahi[(size_t)(rb + row) * H + cb + c16 + 8] = hv[1];
        *(bf16x8*)&Alo[(size_t)(rb + row) * H + cb + c16] = lv[0];
        *(bf16x8*)&Alo[(size_t)(rb + row) * H + cb + c16 + 8] = lv[1];
    }
    __syncthreads();
    {
        bf16x8 hv[2], lv[2];
        #pragma unroll
        for (int q = 0; q < 16; ++q) {
            hv[q >> 3][q & 7] = (short)th[c16 + q][row];
            lv[q >> 3][q & 7] = (short)tl[c16 + q][row];
        }
        *(bf16x8*)&AhiT[(size_t)(cb + row) * H + rb + c16] = hv[0];
        *(bf16x8*)&AhiT[(size_t)(cb + row) * H + rb + c16 + 8] = hv[1];
        *(bf16x8*)&AloT[(size_t)(cb + row) * H + rb + c16] = lv[0];
        *(bf16x8*)&AloT[(size_t)(cb + row) * H + rb + c16 + 8] = lv[1];
    }
    if (bid == 0) {
        #pragma unroll
        for (int rep = 0; rep < 4; ++rep) {
            const int i = tid + rep * 256;
            const float v = h * bvec[i];
            cv[i] = v; v0[i] = v;
        }
    }
}

// ---------------------------------------------------------------------------
// fused chain step: 512 threads, grid 256 (+2048 X blocks when DO_X).
//  blocks [0,256): Q = L * R (64x64 tile, 8 waves, in-block split-K=2,
//                  2-buffer __syncthreads staging via gload_lds, 3-product).
//                  Epilogue: half0 waves reduce+store; half1 waves compute
//                  the fused matvec rows bid*4 .. bid*4+3 in parallel.
//  blocks [256, 2304) (DO_X only): X fp32 -> transposed bf16 plane XhiT.
// BK64: 8 K-iterations of 64 (128KB LDS, halves barrier-drain count);
// BK32: 16 K-iterations of 32 (64KB LDS — used for chain0 so X co-resides).
// ---------------------------------------------------------------------------
template<bool WRITE_N, bool WRITE_T, bool DO_X, bool PR, bool BK64>
__launch_bounds__(512)
__global__ void chain_fused_k(const unsigned short* __restrict__ Lhi,
                              const unsigned short* __restrict__ Llo,
                              const unsigned short* __restrict__ RThi,
                              const unsigned short* __restrict__ RTlo,
                              unsigned short* __restrict__ Qhi,
                              unsigned short* __restrict__ Qlo,
                              unsigned short* __restrict__ QhiT,
                              unsigned short* __restrict__ QloT,
                              const float* __restrict__ vin,
                              const float* __restrict__ addv,
                              float* __restrict__ vout,
                              const float* __restrict__ X,
                              unsigned short* __restrict__ XhiT)
{
    constexpr int BKH = BK64 ? 64 : 32;      // per-half k per stage
    constexpr int NIT = 512 / BKH;           // K iterations
    constexpr int GPR = BKH / 8;             // 16B granules per row

    __shared__ unsigned short sA[2][2][2][64][BKH];  // [dbuf][khalf][plane][row][k]
    __shared__ unsigned short sB[2][2][2][64][BKH];

    const int tid = threadIdx.x;
    const int bid = blockIdx.x;
    const int wave = tid >> 6, lane = tid & 63;

    if (DO_X && bid >= 256) {
        // ---- X transpose blocks: fp32 -> rounded bf16, transposed ----
        float (*ts)[65] = (float(*)[65])&sA[0][0][0][0][0];   // 16.6KB overlay
        const int tile = bid - 256;                            // 0..2047
        const int n0x = (tile >> 4) * 64, k0x = (tile & 15) * 64;
        #pragma unroll
        for (int p = 0; p < 2; ++p) {
            const int kr = p * 32 + (tid >> 4);     // k-local
            const int c4 = (tid & 15) * 4;          // n-local
            const float4 v = *(const float4*)&X[(size_t)(k0x + kr) * BATCH + n0x + c4];
            ts[kr][c4 + 0] = v.x; ts[kr][c4 + 1] = v.y;
            ts[kr][c4 + 2] = v.z; ts[kr][c4 + 3] = v.w;
        }
        __syncthreads();
        {
            const int n = tid >> 3;                 // n-local 0..63
            const int kc = (tid & 7) * 8;           // k-local chunk
            bf16x8 hv;
            #pragma unroll
            for (int q = 0; q < 8; ++q)
                hv[q] = (short)rnd_bf16(ts[kc + q][n]);
            *(bf16x8*)&XhiT[(size_t)(n0x + n) * H + k0x + kc] = hv;
        }
        return;
    }

    // ---- GEMM blocks ----
    const int lg = lane >> 4, lm = lane & 15;
    const int half = wave >> 2;               // k-half owner
    const int wq = wave & 3;
    const int wr2 = (wq >> 1) * 32, wc2 = (wq & 1) * 32;
    // 2D patch per XCD
    const int xcd = bid & 7;
    const int idx0 = bid >> 3;
    const int mt = (xcd >> 1) * 4 + (idx0 & 3);
    const int nt = (xcd & 1) * 8 + (idx0 >> 2);
    const int m0 = mt * 64, n0 = nt * 64;

    f32x4 acc[2][2] = {};

    #define CSTAGE(tt, b) do {                                                     \
        _Pragma("unroll")                                                          \
        for (int it = 0; it < GPR; ++it) {                                         \
            const int idx = tid + it * 512;                                        \
            const int kc = idx % GPR;                                              \
            const int row = (idx / GPR) & 63;                                      \
            const int plane = (idx / (GPR * 64)) & 1;                              \
            const int kh = (idx / (GPR * 128)) & 1;                                \
            const int mat = idx / (GPR * 256);                                     \
            const int ks = BK64 ? (kc ^ (row & 7)) : (kc ^ ((row >> 1) & 3));      \
            const unsigned short* g = mat ? (plane ? RTlo : RThi)                  \
                                          : (plane ? Llo : Lhi);                   \
            const int rb = mat ? n0 : m0;                                          \
            unsigned short* d = mat ? &sB[b][kh][plane][row][kc * 8]               \
                                    : &sA[b][kh][plane][row][kc * 8];              \
            gload16(g + (size_t)(rb + row) * H + kh * 512 + (tt) * BKH + ks * 8, d); \
        }                                                                          \
    } while (0)

    CSTAGE(0, 0);
    __syncthreads();
    int buf = 0;
    for (int t = 0; t < NIT; ++t) {
        if (t + 1 < NIT) CSTAGE(t + 1, buf ^ 1);
        #pragma unroll
        for (int kk = 0; kk < (BK64 ? 2 : 1); ++kk) {
            bf16x8 ah[2], al[2], bh[2], bl[2];
            #pragma unroll
            for (int i = 0; i < 2; ++i) {
                const int row = wr2 + i * 16 + lm;
                const int g = kk * 4 + lg;
                const int sl = BK64 ? (g ^ (row & 7)) : (g ^ ((row >> 1) & 3));
                ah[i] = *(const bf16x8*)&sA[buf][half][0][row][sl * 8];
                al[i] = *(const bf16x8*)&sA[buf][half][1][row][sl * 8];
                const int rn = wc2 + i * 16 + lm;
                const int sn = BK64 ? (g ^ (rn & 7)) : (g ^ ((rn >> 1) & 3));
                bh[i] = *(const bf16x8*)&sB[buf][half][0][rn][sn * 8];
                bl[i] = *(const bf16x8*)&sB[buf][half][1][rn][sn * 8];
            }
            #pragma unroll
            for (int i = 0; i < 2; ++i)
                #pragma unroll
                for (int j = 0; j < 2; ++j) {
                    acc[i][j] = __builtin_amdgcn_mfma_f32_16x16x32_bf16(ah[i], bh[j], acc[i][j], 0, 0, 0);
                    acc[i][j] = __builtin_amdgcn_mfma_f32_16x16x32_bf16(ah[i], bl[j], acc[i][j], 0, 0, 0);
                    acc[i][j] = __builtin_amdgcn_mfma_f32_16x16x32_bf16(al[i], bh[j], acc[i][j], 0, 0, 0);
                }
        }
        __syncthreads();
        buf ^= 1;
    }
    #undef CSTAGE

    // cross-half reduce via LDS (stride 17 floats)
    float* red = (float*)&sA[0][0][0][0][0];
    const int ridx = wq * 64 + lane;
    if (half == 1) {
        float* dst = red + (size_t)ridx * 17;
        #pragma unroll
        for (int i = 0; i < 2; ++i)
            #pragma unroll
            for (int j = 0; j < 2; ++j)
                *(f32x4*)&dst[(i * 2 + j) * 4] = acc[i][j];
    }
    __syncthreads();
    if (half == 0) {
        const float* src = red + (size_t)ridx * 17;
        #pragma unroll
        for (int i = 0; i < 2; ++i)
            #pragma unroll
            for (int j = 0; j < 2; ++j) {
                const f32x4 p = *(const f32x4*)&src[(i * 2 + j) * 4];
                acc[i][j] += p;
            }
        #pragma unroll
        for (int i = 0; i < 2; ++i) {
            const int row0 = m0 + wr2 + i * 16 + lg * 4;
            #pragma unroll
            for (int j = 0; j < 2; ++j) {
                const int col = n0 + wc2 + j * 16 + lm;
                if (PR) {
                    // final step: single rounded bf16 plane (big GEMM input)
                    #pragma unroll
                    for (int r = 0; r < 4; ++r)
                        Qhi[(size_t)(row0 + r) * H + col] = rnd_bf16(acc[i][j][r]);
                } else {
                    unsigned short hs[4], ls[4];
                    #pragma unroll
                    for (int r = 0; r < 4; ++r) {
                        split2(acc[i][j][r], hs[r], ls[r]);
                        if (WRITE_N) {
                            Qhi[(size_t)(row0 + r) * H + col] = hs[r];
                            Qlo[(size_t)(row0 + r) * H + col] = ls[r];
                        }
                    }
                    if (WRITE_T) {
                        ushort4 th, tl;
                        th.x = hs[0]; th.y = hs[1]; th.z = hs[2]; th.w = hs[3];
                        tl.x = ls[0]; tl.y = ls[1]; tl.z = ls[2]; tl.w = ls[3];
                        *(ushort4*)&QhiT[(size_t)col * H + row0] = th;
                        *(ushort4*)&QloT[(size_t)col * H + row0] = tl;
                    }
                }
            }
        }
    } else {
        // ---- fused matvec: waves 4..7 handle row bid*4 + (wave-4) ----
        const int r = bid * 4 + (wave & 3);
        const unsigned short* mh = Lhi + (size_t)r * H + lane * 16;
        const unsigned short* ml = Llo + (size_t)r * H + lane * 16;
        const float4* xq = (const float4*)vin + lane * 4;
        float4 xv[4];
        #pragma unroll
        for (int q = 0; q < 4; ++q) xv[q] = xq[q];
        bf16x8 h0 = *(const bf16x8*)&mh[0];
        bf16x8 h1 = *(const bf16x8*)&mh[8];
        bf16x8 l0 = *(const bf16x8*)&ml[0];
        bf16x8 l1 = *(const bf16x8*)&ml[8];
        float s = 0.0f;
        const float* xf = (const float*)xv;
        #pragma unroll
        for (int q = 0; q < 8; ++q) {
            const float m0v = bf2f((unsigned short)h0[q]) + bf2f((unsigned short)l0[q]);
            const float m1v = bf2f((unsigned short)h1[q]) + bf2f((unsigned short)l1[q]);
            s = fmaf(m0v, xf[q], s);
            s = fmaf(m1v, xf[8 + q], s);
        }
        #pragma unroll
        for (int off = 32; off; off >>= 1)
            s += __shfl_down(s, off, 64);
        if (lane == 0) vout[r] = addv[r] + s;
    }
}

// ---------------------------------------------------------------------------
// big GEMM, bf16 x bf16 (1 MFMA per fragment): C = Pr * Xh + bias.
// 128x128 tile, 256 threads (4 waves, 64x64 each), BK=32, 3-buffer
// counted-vmcnt pipe. grid 512 = 2 blocks/CU, 48KB LDS.
// ---------------------------------------------------------------------------
__launch_bounds__(256)
__global__ void big_gemm1_k(const unsigned short* __restrict__ Pr,
                            const unsigned short* __restrict__ XhiT,
                            float* __restrict__ C, const float* __restrict__ bias)
{
    __shared__ unsigned short sA[3][128][32];   // 24KB
    __shared__ unsigned short sB[3][128][32];   // 24KB

    const int tid = threadIdx.x;
    const int wave = tid >> 6, lane = tid & 63;
    const int lg = lane >> 4, lm = lane & 15;
    const int wr2 = (wave >> 1) * 64;    // wave tile 64x64
    const int wc2 = (wave & 1) * 64;
    const int bid = blockIdx.x;
    const int l = bid >> 3;              // 0..63
    const int m0 = (l & 7) * 128;
    const int n0 = ((bid & 7) * 8 + (l >> 3)) * 128;

    f32x4 acc[4][4] = {};

    #define BSTAGE(tt, b) do {                                                   \
        _Pragma("unroll")                                                        \
        for (int it = 0; it < 2; ++it) {                                         \
            const int idx = tid + it * 256;                                      \
            const int row = idx >> 2, kc = idx & 3;                              \
            const int ks = kc ^ ((row >> 1) & 3);                                \
            const size_t go = (size_t)(tt) * 32 + ks * 8;                        \
            gload16(Pr   + (size_t)(m0 + row) * H + go, &sA[b][row][kc * 8]);    \
            gload16(XhiT + (size_t)(n0 + row) * H + go, &sB[b][row][kc * 8]);    \
        }                                                                        \
    } while (0)

    BSTAGE(0, 0);
    BSTAGE(1, 1);
    VMCNT(4);
    RBAR();

    #pragma unroll
    for (int t = 0; t < 32; ++t) {
        const int b = t % 3;
        bf16x8 ah[4], bh[4];
        #pragma unroll
        for (int i = 0; i < 4; ++i) {
            const int row = wr2 + i * 16 + lm;
            const int sl = lg ^ ((row >> 1) & 3);
            ah[i] = *(const bf16x8*)&sA[b][row][sl * 8];
            const int rn = wc2 + i * 16 + lm;
            const int sn = lg ^ ((rn >> 1) & 3);
            bh[i] = *(const bf16x8*)&sB[b][rn][sn * 8];
        }
        if (t + 2 < 32) BSTAGE(t + 2, (t + 2) % 3);
        __builtin_amdgcn_s_setprio(1);
        #pragma unroll
        for (int i = 0; i < 4; ++i)
            #pragma unroll
            for (int j = 0; j < 4; ++j)
                acc[i][j] = __builtin_amdgcn_mfma_f32_16x16x32_bf16(ah[i], bh[j], acc[i][j], 0, 0, 0);
        __builtin_amdgcn_s_setprio(0);
        if (t < 30) VMCNT(4);        // wait only for stage t+1's 4 loads
        else if (t == 30) VMCNT(0);
        if (t < 31) RBAR();
    }
    #undef BSTAGE

    #pragma unroll
    for (int i = 0; i < 4; ++i) {
        const int row0 = m0 + wr2 + i * 16 + lg * 4;
        #pragma unroll
        for (int r = 0; r < 4; ++r) {
            const float bv = bias[row0 + r];
            float* dst = &C[(size_t)(row0 + r) * BATCH + n0 + wc2 + lm];
            #pragma unroll
            for (int j = 0; j < 4; ++j)
                dst[j * 16] = acc[i][j][r] + bv;
        }
    }
}

// ---------------------------------------------------------------------------
// big GEMM fallback (X split in-kernel, no XT needed) — 3-product
// ---------------------------------------------------------------------------
#define PADK 40

__launch_bounds__(256)
__global__ void big_gemm_k(const unsigned short* __restrict__ Ahi_g,
                           const unsigned short* __restrict__ Alo_g,
                           const float* __restrict__ X, float* __restrict__ C,
                           const float* __restrict__ bias)
{
    __shared__ unsigned short Ahi[128][PADK], Alo[128][PADK];
    __shared__ unsigned short Bhi[128][PADK], Blo[128][PADK];

    const int tid = threadIdx.x;
    const int wave = tid >> 6;
    const int lane = tid & 63;
    const int wr = (wave >> 1) * 64;
    const int wc = (wave & 1) * 64;
    const int m0 = blockIdx.y * 128;
    const int n0 = blockIdx.x * 128;
    const int lg = lane >> 4;
    const int lm = lane & 15;

    f32x4 acc[4][4] = {};

    for (int k0 = 0; k0 < H; k0 += 32) {
        #pragma unroll
        for (int a2 = 0; a2 < 2; ++a2) {
            const int id = tid + a2 * 256;
            const int row = id >> 2;
            const int ko = id & 3;
            const size_t g = (size_t)(m0 + row) * H + k0 + ko * 8;
            *(bf16x8*)&Ahi[row][ko * 8] = *(const bf16x8*)&Ahi_g[g];
            *(bf16x8*)&Alo[row][ko * 8] = *(const bf16x8*)&Alo_g[g];
        }
        #pragma unroll
        for (int a2 = 0; a2 < 2; ++a2) {
            const int id = tid + a2 * 256;
            const int n = id & 127;
            const int ko = id >> 7;
            const float* src = &X[(size_t)(k0 + ko * 8) * BATCH + n0 + n];
            bf16x8 bh, bl;
            #pragma unroll
            for (int i = 0; i < 8; ++i) {
                unsigned short hh, ll;
                split2(src[(size_t)i * BATCH], hh, ll);
                bh[i] = (short)hh;
                bl[i] = (short)ll;
            }
            *(bf16x8*)&Bhi[n][ko * 8] = bh;
            *(bf16x8*)&Blo[n][ko * 8] = bl;
        }
        __syncthreads();

        bf16x8 ah[4], al[4], bh[4], bl[4];
        #pragma unroll
        for (int i = 0; i < 4; ++i) {
            const int m = wr + i * 16 + lm;
            ah[i] = *(const bf16x8*)&Ahi[m][lg * 8];
            al[i] = *(const bf16x8*)&Alo[m][lg * 8];
            const int n = wc + i * 16 + lm;
            bh[i] = *(const bf16x8*)&Bhi[n][lg * 8];
            bl[i] = *(const bf16x8*)&Blo[n][lg * 8];
        }
        #pragma unroll
        for (int i = 0; i < 4; ++i)
            #pragma unroll
            for (int j = 0; j < 4; ++j) {
                acc[i][j] = __builtin_amdgcn_mfma_f32_16x16x32_bf16(ah[i], bh[j], acc[i][j], 0, 0, 0);
                acc[i][j] = __builtin_amdgcn_mfma_f32_16x16x32_bf16(ah[i], bl[j], acc[i][j], 0, 0, 0);
                acc[i][j] = __builtin_amdgcn_mfma_f32_16x16x32_bf16(al[i], bh[j], acc[i][j], 0, 0, 0);
            }
        __syncthreads();
    }

    #pragma unroll
    for (int i = 0; i < 4; ++i) {
        const int rowb = m0 + wr + i * 16 + lg * 4;
        #pragma unroll
        for (int r = 0; r < 4; ++r) {
            const float bv = bias[rowb + r];
            float* dst = &C[(size_t)(rowb + r) * BATCH + n0 + wc + lm];
            #pragma unroll
            for (int j = 0; j < 4; ++j)
                dst[j * 16] = acc[i][j][r] + bv;
        }
    }
}

// ---------------------------------------------------------------------------
// host-side launcher
// ---------------------------------------------------------------------------
extern "C" void kernel_launch(void* const* d_in, const int* in_sizes, int n_in,
                              void* d_out, int out_size, void* d_ws, size_t ws_size,
                              hipStream_t stream)
{
    const float* x0 = (const float*)d_in[0];
    const float* t0 = (const float*)d_in[1];
    const float* t1 = (const float*)d_in[2];
    const float* W  = (const float*)d_in[3];
    const float* bb = (const float*)d_in[4];
    float* out = (float*)d_out;

    // ws layout: A planes {hi,lo,hiT,loT} (8MB) | cv,v0,v1 | @16MB: XhiT (16MB)
    unsigned short* Aplanes = (unsigned short*)d_ws;
    unsigned short* Ahi  = Aplanes;
    unsigned short* Alo  = Aplanes + HH;
    float* cv = (float*)(Aplanes + 4 * HH);
    float* v0 = cv + H;
    float* v1 = v0 + H;

    const size_t xtoff = (size_t)16 * 1024 * 1024;
    const bool useXT = ws_size >= xtoff + (size_t)BATCH * H * sizeof(unsigned short);
    unsigned short* XhiT = (unsigned short*)((char*)d_ws + xtoff);

    // d_out scratch: two ping-pong plane-sets {hi,lo,hiT,loT}, 8MB each (16MB),
    // fully overwritten by the final 32MB C write.
    unsigned short* PA = (unsigned short*)d_out;
    unsigned short* PB = PA + (size_t)4 * HH;

    setup_k<<<256, 256, 0, stream>>>(W, bb, t0, t1, Aplanes, cv, v0);

    // addition chain 1 -> 2 -> 3 -> 6 -> 12 -> 24 -> 25 -> 50
    // seq: s=0 SQ, 1 MUL, 2 SQ, 3 SQ, 4 SQ, 5 MUL, 6 SQ
    // Planes written per consumer: s=0,4 feed MUL (L=A) -> T planes only;
    // s=1,2,3,5 -> normal + T; s=6 -> rounded single plane (big GEMM).
    const int seq[7] = {0, 1, 0, 0, 0, 1, 0};
    unsigned short* cur = Ahi;                  // P_1 = A (4 consecutive planes)
    float* vin = v0;
    float* vout = v1;
    for (int s = 0; s < 7; ++s) {
        const unsigned short* L  = seq[s] ? Ahi : cur;
        const unsigned short* Ll = seq[s] ? Alo : cur + HH;
        const float* addv = seq[s] ? cv : vin;
        if (s == 0) {
            unsigned short* nxt = PA;
            if (useXT) {
                chain_fused_k<false, true, true, false, false><<<2304, 512, 0, stream>>>(
                    L, Ll, cur + 2 * HH, cur + 3 * HH,
                    nxt, nxt + HH, nxt + 2 * HH, nxt + 3 * HH,
                    vin, addv, vout, x0, XhiT);
            } else {
                chain_fused_k<false, true, false, false, false><<<256, 512, 0, stream>>>(
                    L, Ll, cur + 2 * HH, cur + 3 * HH,
                    nxt, nxt + HH, nxt + 2 * HH, nxt + 3 * HH,
                    vin, addv, vout, nullptr, nullptr);
            }
            cur = nxt;
        } else if (s == 4) {
            unsigned short* nxt = PA;   // s=4 even -> PA
            chain_fused_k<false, true, false, false, true><<<256, 512, 0, stream>>>(
                L, Ll, cur + 2 * HH, cur + 3 * HH,
                nxt, nxt + HH, nxt + 2 * HH, nxt + 3 * HH,
                vin, addv, vout, nullptr, nullptr);
            cur = nxt;
        } else if (s < 6) {
            unsigned short* nxt = (s & 1) ? PB : PA;
            chain_fused_k<true, true, false, false, true><<<256, 512, 0, stream>>>(
                L, Ll, cur + 2 * HH, cur + 3 * HH,
                nxt, nxt + HH, nxt + 2 * HH, nxt + 3 * HH,
                vin, addv, vout, nullptr, nullptr);
            cur = nxt;
        } else if (useXT) {
            // final step: write ONLY the rounded single plane Pr -> Ahi
            chain_fused_k<false, false, false, true, true><<<256, 512, 0, stream>>>(
                L, Ll, cur + 2 * HH, cur + 3 * HH,
                Ahi, nullptr, nullptr, nullptr,
                vin, addv, vout, nullptr, nullptr);
            cur = Ahi;
        } else {
            // fallback path: final step writes hi/lo planes for big_gemm_k
            chain_fused_k<true, false, false, false, true><<<256, 512, 0, stream>>>(
                L, Ll, cur + 2 * HH, cur + 3 * HH,
                Ahi, Alo, nullptr, nullptr,
                vin, addv, vout, nullptr, nullptr);
            cur = Ahi;
        }
        float* tv = vin; vin = vout; vout = tv;
    }
    // cur = P_50 (Pr single plane in Ahi if useXT); vin = v_50

    if (useXT) {
        big_gemm1_k<<<512, 256, 0, stream>>>(Ahi, XhiT, out, vin);
    } else {
        big_gemm_k<<<dim3(BATCH / 128, H / 128), 256, 0, stream>>>(
            Ahi, Alo, x0, out, vin);
    }
}